// Round 7
// baseline (3774.545 us; speedup 1.0000x reference)
//
#include <hip/hip_runtime.h>
#include <math.h>

// Problem constants
#define B_    32
#define CIN   4
#define SLEN  2048
#define NF    256
#define HD    256          // LSTM hidden per direction
#define SP    341          // post conv+pool sequence length
#define RTOT  (B_*SP)      // 10912 rows
#define NH_   8
#define DH_   64
#define GRP   4            // batches per attention group
#define PSTR  344          // padded P row stride (16B-aligned)
#define HS    (SP*HD)      // 87296: per-dir h elems

typedef __attribute__((ext_vector_type(8))) short short8;
typedef __attribute__((ext_vector_type(4))) float floatx4;
typedef __attribute__((ext_vector_type(4))) unsigned short ushortx4;
typedef __attribute__((ext_vector_type(8))) unsigned short ushort8;

__device__ __forceinline__ float sigmoidf_(float x) { return 1.0f / (1.0f + expf(-x)); }

__device__ __forceinline__ unsigned short f2bf(float x) {
    unsigned int u = __float_as_uint(x);
    unsigned int r = (u + 0x7FFF + ((u >> 16) & 1)) >> 16;   // RNE
    return (unsigned short)r;
}
__device__ __forceinline__ float bf2f(unsigned short b) {
    return __uint_as_float(((unsigned int)b) << 16);
}

// ---------------------------------------------------------------------------
// Packed bf16 hi/lo "octet" layout: for a row of K fp32 values, the packed row
// has 2K ushorts: octet o (elems 8o..8o+7) occupies ushorts [16o..16o+7]=hi,
// [16o+8..16o+15]=lo.  One K-step of 32 elems = 128 contiguous bytes.
// ---------------------------------------------------------------------------

// Kernel 1: Conv1d(4->256,k13,pad6)+BN+ReLU+MaxPool1d(6) -> x0 packed
__global__ __launch_bounds__(256)
void conv_pool_k(const float* __restrict__ in, const float* __restrict__ cw,
                 const float* __restrict__ gamma, const float* __restrict__ beta,
                 unsigned short* __restrict__ x0p)
{
    const int b  = blockIdx.y;
    const int s0 = blockIdx.x * 16;
    const int co = threadIdx.x;
    __shared__ float ins[CIN][16*6 + 12];
    for (int idx = threadIdx.x; idx < CIN*108; idx += 256) {
        int ci = idx / 108, o = idx % 108;
        int pos = 6*s0 - 6 + o;
        ins[ci][o] = (pos >= 0 && pos < SLEN) ? in[(b*CIN + ci)*SLEN + pos] : 0.0f;
    }
    float wreg[52];
    {
        const float4* wp = (const float4*)(cw + co*52);
        #pragma unroll
        for (int j4 = 0; j4 < 13; ++j4) {
            float4 w4 = wp[j4];
            wreg[j4*4+0]=w4.x; wreg[j4*4+1]=w4.y; wreg[j4*4+2]=w4.z; wreg[j4*4+3]=w4.w;
        }
    }
    const float scale = gamma[co] * (1.0f / sqrtf(1.0f + 1e-5f));
    const float shift = beta[co];
    __syncthreads();
    for (int si = 0; si < 16; ++si) {
        int s = s0 + si;
        if (s >= SP) break;
        float win[CIN][18];
        #pragma unroll
        for (int ci = 0; ci < CIN; ++ci)
            #pragma unroll
            for (int o = 0; o < 18; ++o)
                win[ci][o] = ins[ci][6*si + o];
        float m = -1e30f;
        #pragma unroll
        for (int p6 = 0; p6 < 6; ++p6) {
            float acc = 0.0f;
            #pragma unroll
            for (int ci = 0; ci < CIN; ++ci)
                #pragma unroll
                for (int kk = 0; kk < 13; ++kk)
                    acc += win[ci][p6+kk] * wreg[ci*13+kk];
            float val = acc * scale + shift;
            val = fmaxf(val, 0.0f);
            m = fmaxf(m, val);
        }
        unsigned short hb_ = f2bf(m);
        unsigned short lb_ = f2bf(m - bf2f(hb_));
        size_t rb = (size_t)(b*SP + s)*512 + (size_t)(co >> 3)*16 + (co & 7);
        x0p[rb]     = hb_;
        x0p[rb + 8] = lb_;
    }
}

// Kernel 2a: fp32 -> separate hi/lo pack (for lstm Whh, layout unchanged)
__global__ __launch_bounds__(256)
void pack4_k(const float* __restrict__ W, unsigned short* __restrict__ hi,
             unsigned short* __restrict__ lo, int n4)
{
    int i = blockIdx.x * 256 + threadIdx.x;
    if (i >= n4) return;
    float4 x = *((const float4*)W + i);
    float v[4] = {x.x, x.y, x.z, x.w};
    ushortx4 h, l;
    #pragma unroll
    for (int e = 0; e < 4; ++e) {
        unsigned short hb = f2bf(v[e]);
        h[e] = hb;
        l[e] = f2bf(v[e] - bf2f(hb));
    }
    *((ushortx4*)hi + i) = h;
    *((ushortx4*)lo + i) = l;
}

// Kernel 2b: fp32 -> interleaved octet pack (8 elems/thread)
__global__ __launch_bounds__(256)
void pack8_k(const float* __restrict__ W, unsigned short* __restrict__ O, int n8)
{
    int i = blockIdx.x * 256 + threadIdx.x;
    if (i >= n8) return;
    const float4* wp = (const float4*)W + (size_t)i*2;
    float4 a = wp[0], b = wp[1];
    float v[8] = {a.x,a.y,a.z,a.w,b.x,b.y,b.z,b.w};
    ushort8 h, l;
    #pragma unroll
    for (int e = 0; e < 8; ++e) {
        unsigned short hb = f2bf(v[e]);
        h[e] = hb;
        l[e] = f2bf(v[e] - bf2f(hb));
    }
    *(ushort8*)(O + (size_t)i*16)     = h;
    *(ushort8*)(O + (size_t)i*16 + 8) = l;
}

// ---------------------------------------------------------------------------
// Kernel 3: split-bf16 MFMA GEMM, operands in packed octet layout.
// (unchanged from round 3)
// ---------------------------------------------------------------------------
template<int RELU>
__global__ __launch_bounds__(256)
void gemm_bf_k(const unsigned short* __restrict__ Ap, const unsigned short* __restrict__ Bp,
               const float* __restrict__ bias, float* __restrict__ C,
               int M, int N, int K)
{
    const int n0 = blockIdx.x * 128;
    const int m0 = blockIdx.y * 128;
    const int tid = threadIdx.x;
    const int lane = tid & 63;
    const int w = tid >> 6;
    const int wm = w >> 1, wn = w & 1;
    const int ln15 = lane & 15, lq = lane >> 4;
    const int l8 = lane >> 3, lj = lane & 7;
    const size_t rstr = 2*(size_t)K;

    __shared__ unsigned short As[128*64];
    __shared__ unsigned short Bs[128*64];

    floatx4 acc[4][4];
    #pragma unroll
    for (int i = 0; i < 4; ++i)
        #pragma unroll
        for (int j = 0; j < 4; ++j) acc[i][j] = (floatx4){0.f, 0.f, 0.f, 0.f};

    int rloc[4];
    #pragma unroll
    for (int c = 0; c < 4; ++c) rloc[c] = w*32 + c*8 + l8;
    const int spos = lj ^ (l8 & 7);

    for (int k0 = 0; k0 < K; k0 += 32) {
        short8 va[4], vb[4];
        #pragma unroll
        for (int c = 0; c < 4; ++c) {
            int gra = m0 + rloc[c]; if (gra >= M) gra = M - 1;
            va[c] = *(const short8*)(Ap + (size_t)gra*rstr + k0*2 + lj*8);
            vb[c] = *(const short8*)(Bp + (size_t)(n0 + rloc[c])*rstr + k0*2 + lj*8);
        }
        __syncthreads();
        #pragma unroll
        for (int c = 0; c < 4; ++c) {
            *(short8*)&As[rloc[c]*64 + spos*8] = va[c];
            *(short8*)&Bs[rloc[c]*64 + spos*8] = vb[c];
        }
        __syncthreads();

        short8 fa_h[4], fa_l[4], fb_h[4], fb_l[4];
        #pragma unroll
        for (int mt = 0; mt < 4; ++mt) {
            const int lr = wm*64 + mt*16 + ln15;
            fa_h[mt] = *(const short8*)&As[lr*64 + (((lq*2  ) ^ (lr&7))*8)];
            fa_l[mt] = *(const short8*)&As[lr*64 + (((lq*2+1) ^ (lr&7))*8)];
        }
        #pragma unroll
        for (int nt = 0; nt < 4; ++nt) {
            const int lr = wn*64 + nt*16 + ln15;
            fb_h[nt] = *(const short8*)&Bs[lr*64 + (((lq*2  ) ^ (lr&7))*8)];
            fb_l[nt] = *(const short8*)&Bs[lr*64 + (((lq*2+1) ^ (lr&7))*8)];
        }
        #pragma unroll
        for (int mt = 0; mt < 4; ++mt)
            #pragma unroll
            for (int nt = 0; nt < 4; ++nt) {
                acc[mt][nt] = __builtin_amdgcn_mfma_f32_16x16x32_bf16(fa_l[mt], fb_h[nt], acc[mt][nt], 0, 0, 0);
                acc[mt][nt] = __builtin_amdgcn_mfma_f32_16x16x32_bf16(fa_h[mt], fb_l[nt], acc[mt][nt], 0, 0, 0);
                acc[mt][nt] = __builtin_amdgcn_mfma_f32_16x16x32_bf16(fa_h[mt], fb_h[nt], acc[mt][nt], 0, 0, 0);
            }
    }

    #pragma unroll
    for (int nt = 0; nt < 4; ++nt) {
        const int n = n0 + wn*64 + nt*16 + ln15;
        const float bv = bias[n];
        #pragma unroll
        for (int mt = 0; mt < 4; ++mt) {
            const int mbase = m0 + wm*64 + mt*16 + lq*4;
            #pragma unroll
            for (int r = 0; r < 4; ++r) {
                int m = mbase + r;
                if (m < M) {
                    float val = acc[mt][nt][r] + bv;
                    if (RELU) val = fmaxf(val, 0.0f);
                    C[(size_t)m*N + n] = val;
                }
            }
        }
    }
}

// ---------------------------------------------------------------------------
// Kernel 3b: SYNC-FREE LSTM scan.  Key fact: h_new[row] depends only on
// h[row] — the recurrence is row-local.  Each block owns 16 rows x ALL 256
// h-cols (all 1024 gates) for one direction: fully self-contained, 32 steps
// looped internally with only __syncthreads.  Grid (22, 2) = 44 blocks,
// plain launch (no cooperative, no global barrier, no LLC ops).
//   h: LDS double buffer [2][16][256] fp32, XOR-swizzled 32B chunks.
//   c: registers (thread owns its 16 cells for the whole scan).
//   Wave jq handles j in [jq*64,(jq+1)*64) x all 4 gates: nt = gate*4+j16.
//   D-frag: n=lane&15, m=(lane>>4)*4+r -> the 4 gates of cell (row,j) are in
//   the SAME lane at nt = {0..3}*4+j16, reg r: epilogue is lane-local (no Csh).
// ---------------------------------------------------------------------------
__global__ __launch_bounds__(256)
void lstm_scan_k(const float* __restrict__ G,              // [32*341][2048]
                 const unsigned short* __restrict__ Whi,   // [2][1024][256]
                 const unsigned short* __restrict__ Wlo,
                 unsigned short* __restrict__ x_out)       // [32*341] packed rows of 512
{
    const int m0 = blockIdx.x * 16;
    const int d  = blockIdx.y;
    const int tid = threadIdx.x;
    const int jq = tid >> 6;              // wave = j-quarter
    const int lane = tid & 63;
    const int ln15 = lane & 15, lq = lane >> 4;

    __shared__ float hbuf[2][16][256];

    const unsigned short* WhiD = Whi + (size_t)d*1024*256;
    const unsigned short* WloD = Wlo + (size_t)d*1024*256;

    // B rows for this wave's 16 n-tiles: nt = gate*4 + j16
    int brow[16];
    #pragma unroll
    for (int gate = 0; gate < 4; ++gate)
        #pragma unroll
        for (int j16 = 0; j16 < 4; ++j16)
            brow[gate*4 + j16] = gate*256 + jq*64 + j16*16 + ln15;

    float creg[4][4];   // c-state: [j16][r]
    #pragma unroll
    for (int a = 0; a < 4; ++a)
        #pragma unroll
        for (int b = 0; b < 4; ++b) creg[a][b] = 0.0f;

    for (int s = 0; s < B_; ++s) {
        const int t_in = d ? (B_ - 1 - s) : s;
        const int rb = s & 1, wb = (s + 1) & 1;

        floatx4 acc[16];
        #pragma unroll
        for (int t = 0; t < 16; ++t) acc[t] = (floatx4){0.f, 0.f, 0.f, 0.f};

        if (s > 0) {
            #pragma unroll
            for (int kk = 0; kk < 8; ++kk) {
                // A-frag: row=ln15, k=kk*32+lq*8+e.  Swizzled chunk read.
                const int cs = (kk*4 + lq) ^ (ln15 & 7);
                const float* hp = &hbuf[rb][ln15][cs*8];
                float4 v0 = *(const float4*)hp;
                float4 v1 = *(const float4*)(hp + 4);
                float vv[8] = {v0.x, v0.y, v0.z, v0.w, v1.x, v1.y, v1.z, v1.w};
                short8 ahi, alo;
                #pragma unroll
                for (int e = 0; e < 8; ++e) {
                    unsigned short hb16 = f2bf(vv[e]);
                    ahi[e] = (short)hb16;
                    alo[e] = (short)f2bf(vv[e] - bf2f(hb16));
                }
                const int ko = kk*32 + lq*8;
                #pragma unroll
                for (int t = 0; t < 16; ++t) {
                    short8 bhi = *(const short8*)(WhiD + (size_t)brow[t]*HD + ko);
                    short8 blo = *(const short8*)(WloD + (size_t)brow[t]*HD + ko);
                    acc[t] = __builtin_amdgcn_mfma_f32_16x16x32_bf16(alo, bhi, acc[t], 0, 0, 0);
                    acc[t] = __builtin_amdgcn_mfma_f32_16x16x32_bf16(ahi, blo, acc[t], 0, 0, 0);
                    acc[t] = __builtin_amdgcn_mfma_f32_16x16x32_bf16(ahi, bhi, acc[t], 0, 0, 0);
                }
            }
        }

        // epilogue: lane-local gates.  Cell (row = lq*4+r, j = jq*64+j16*16+ln15):
        // gate g value = acc[g*4 + j16][r].
        #pragma unroll
        for (int r = 0; r < 4; ++r) {
            const int row = lq*4 + r;
            const int em  = m0 + row;
            if (em < SP) {
                const size_t gbase = ((size_t)t_in*SP + em)*2048 + (size_t)d*1024 + jq*64 + ln15;
                #pragma unroll
                for (int j16 = 0; j16 < 4; ++j16) {
                    const int j = jq*64 + j16*16 + ln15;
                    float gi = acc[ 0 + j16][r] + G[gbase + j16*16 +   0];
                    float gf = acc[ 4 + j16][r] + G[gbase + j16*16 + 256];
                    float gg = acc[ 8 + j16][r] + G[gbase + j16*16 + 512];
                    float go = acc[12 + j16][r] + G[gbase + j16*16 + 768];
                    float cn = sigmoidf_(gf)*creg[j16][r] + sigmoidf_(gi)*tanhf(gg);
                    creg[j16][r] = cn;
                    float hv = sigmoidf_(go)*tanhf(cn);
                    // h -> LDS (swizzled)
                    const int ch = j >> 3, el = j & 7;
                    const int cs = ch ^ (row & 7);
                    hbuf[wb][row][cs*8 + el] = hv;
                    // packed x_out
                    const int colg = d*HD + j;
                    size_t xb = ((size_t)t_in*SP + em)*1024 + (size_t)(colg >> 3)*16 + (colg & 7);
                    unsigned short hb16 = f2bf(hv);
                    x_out[xb]     = hb16;
                    x_out[xb + 8] = f2bf(hv - bf2f(hb16));
                }
            }
        }
        __syncthreads();   // h[wb] visible to all waves; h[rb] reads complete
    }
}

// ---------------------------------------------------------------------------
// Kernel 4a: scores tile (64x64), RPE analytic.
// ---------------------------------------------------------------------------
__global__ __launch_bounds__(256)
void scores_k(const float* __restrict__ q, const float* __restrict__ k,
              float* __restrict__ P, int g)
{
    const int h = blockIdx.z, bl = blockIdx.y, bg = g*GRP + bl;
    const int q0 = (blockIdx.x / 6) * 64;
    const int k0 = (blockIdx.x % 6) * 64;
    const int tid = threadIdx.x;
    __shared__ float qs[64][68];
    __shared__ float ks[64][68];
    {
        int jr = tid >> 2, c16 = (tid & 3) * 16;
        int qq = q0 + jr; if (qq > SP-1) qq = SP-1;
        int kr = k0 + jr; if (kr > SP-1) kr = SP-1;
        const float* qp = &q[((size_t)bg*SP + qq)*512 + h*64 + c16];
        const float* kp = &k[((size_t)bg*SP + kr)*512 + h*64 + c16];
        #pragma unroll
        for (int u = 0; u < 4; ++u) {
            *(float4*)&qs[jr][c16 + u*4] = *(const float4*)(qp + u*4);
            *(float4*)&ks[jr][c16 + u*4] = *(const float4*)(kp + u*4);
        }
    }
    __syncthreads();
    const int tx = tid & 15, ty = tid >> 4;
    float acc[4][4];
    #pragma unroll
    for (int i = 0; i < 4; ++i)
        #pragma unroll
        for (int j = 0; j < 4; ++j) acc[i][j] = 0.0f;
    for (int d4 = 0; d4 < 64; d4 += 4) {
        float4 a[4], b[4];
        #pragma unroll
        for (int i = 0; i < 4; ++i) a[i] = *(const float4*)&qs[ty + 16*i][d4];
        #pragma unroll
        for (int j = 0; j < 4; ++j) b[j] = *(const float4*)&ks[tx + 16*j][d4];
        #pragma unroll
        for (int i = 0; i < 4; ++i)
            #pragma unroll
            for (int j = 0; j < 4; ++j)
                acc[i][j] += a[i].x*b[j].x + a[i].y*b[j].y + a[i].z*b[j].z + a[i].w*b[j].w;
    }
    #pragma unroll
    for (int i = 0; i < 4; ++i) {
        int qq = q0 + ty + 16*i;
        if (qq >= SP) continue;
        int r0 = 6*qq - 1; if (r0 < 0) r0 = 0;
        int r1 = 6*qq + 7; if (r1 > SLEN-1) r1 = SLEN-1;
        size_t rowb = ((size_t)(h*GRP + bl)*SP + qq) * PSTR;
        #pragma unroll
        for (int j = 0; j < 4; ++j) {
            int kk = k0 + tx + 16*j;
            if (kk >= SP) continue;
            int c0 = 6*kk - 1; if (c0 < 0) c0 = 0;
            int c1 = 6*kk + 7;
            int dd1 = c1 - r0; if (dd1 < 0) dd1 = -dd1;
            int dd2 = r1 - c0; if (dd2 < 0) dd2 = -dd2;
            int den = dd1 > dd2 ? dd1 : dd2;
            P[rowb + kk] = (acc[i][j] * 0.125f) * 2047.0f / (float)den;
        }
    }
}

// ---------------------------------------------------------------------------
// Kernel 4b: row softmax in place.
// ---------------------------------------------------------------------------
__global__ __launch_bounds__(256)
void softmax_k(float* __restrict__ P)
{
    const int tid = threadIdx.x;
    const int row = blockIdx.x * 4 + (tid >> 6);
    const int lane = tid & 63;
    float* rp = P + (size_t)row * PSTR;
    float v[6];
    float m = -1e30f;
    #pragma unroll
    for (int i = 0; i < 6; ++i) {
        int col = lane + 64*i;
        v[i] = (col < SP) ? rp[col] : -1e30f;
        m = fmaxf(m, v[i]);
    }
    #pragma unroll
    for (int o = 1; o < 64; o <<= 1) m = fmaxf(m, __shfl_xor(m, o, 64));
    float s = 0.0f;
    #pragma unroll
    for (int i = 0; i < 6; ++i) {
        v[i] = expf(v[i] - m);
        s += v[i];
    }
    #pragma unroll
    for (int o = 1; o < 64; o <<= 1) s += __shfl_xor(s, o, 64);
    float inv = 1.0f / s;
    #pragma unroll
    for (int i = 0; i < 6; ++i) {
        int col = lane + 64*i;
        if (col < SP) rp[col] = v[i] * inv;
    }
}

// ---------------------------------------------------------------------------
// Kernel 4c: out = relu(P @ V), K=SP in 6x64 chunks. cat written PACKED.
// ---------------------------------------------------------------------------
__global__ __launch_bounds__(256)
void pv_k(const float* __restrict__ P, const float* __restrict__ v,
          unsigned short* __restrict__ catp, int g)
{
    const int h = blockIdx.z, bl = blockIdx.y, bg = g*GRP + bl;
    const int q0 = blockIdx.x * 64;
    const int tid = threadIdx.x;
    __shared__ float ps[64][68];
    __shared__ float vs[64][68];
    const int tx = tid & 15, ty = tid >> 4;
    float acc[4][4];
    #pragma unroll
    for (int i = 0; i < 4; ++i)
        #pragma unroll
        for (int j = 0; j < 4; ++j) acc[i][j] = 0.0f;

    for (int kc = 0; kc < 6; ++kc) {
        const int kk0 = kc * 64;
        {
            int jr = tid >> 2, c16 = (tid & 3) * 16;
            int qq = q0 + jr; if (qq > SP-1) qq = SP-1;
            const float* pp = P + ((size_t)(h*GRP + bl)*SP + qq)*PSTR + kk0 + c16;
            #pragma unroll
            for (int u = 0; u < 4; ++u) {
                float4 w = *(const float4*)(pp + u*4);
                int klb = c16 + u*4;
                float vals[4] = {w.x, w.y, w.z, w.w};
                #pragma unroll
                for (int e = 0; e < 4; ++e)
                    ps[klb + e][jr] = (kk0 + klb + e < SP) ? vals[e] : 0.0f;
            }
        }
        {
            int jr = tid >> 2, c16 = (tid & 3) * 16;
            int kr = kk0 + jr; if (kr > SP-1) kr = SP-1;
            const float* vp = &v[((size_t)bg*SP + kr)*512 + h*64 + c16];
            #pragma unroll
            for (int u = 0; u < 4; ++u)
                *(float4*)&vs[jr][c16 + u*4] = *(const float4*)(vp + u*4);
        }
        __syncthreads();
        for (int kk = 0; kk < 64; ++kk) {
            float4 a4 = *(const float4*)&ps[kk][ty*4];
            float4 b4 = *(const float4*)&vs[kk][tx*4];
            float av[4] = {a4.x, a4.y, a4.z, a4.w};
            float bv[4] = {b4.x, b4.y, b4.z, b4.w};
            #pragma unroll
            for (int i = 0; i < 4; ++i)
                #pragma unroll
                for (int j = 0; j < 4; ++j)
                    acc[i][j] += av[i] * bv[j];
        }
        __syncthreads();
    }
    #pragma unroll
    for (int i = 0; i < 4; ++i) {
        int qq = q0 + ty*4 + i;
        if (qq >= SP) continue;
        float r[4];
        r[0] = fmaxf(acc[i][0], 0.0f);
        r[1] = fmaxf(acc[i][1], 0.0f);
        r[2] = fmaxf(acc[i][2], 0.0f);
        r[3] = fmaxf(acc[i][3], 0.0f);
        const int colg = h*64 + tx*4;
        size_t xb = ((size_t)bg*SP + qq)*1024 + (size_t)(colg >> 3)*16 + (colg & 7);
        ushortx4 xh, xl;
        #pragma unroll
        for (int e = 0; e < 4; ++e) {
            unsigned short hb16 = f2bf(r[e]);
            xh[e] = hb16;
            xl[e] = f2bf(r[e] - bf2f(hb16));
        }
        *(ushortx4*)&catp[xb]     = xh;
        *(ushortx4*)&catp[xb + 8] = xl;
    }
}

// ---------------------------------------------------------------------------
extern "C" void kernel_launch(void* const* d_in, const int* in_sizes, int n_in,
                              void* d_out, int out_size, void* d_ws, size_t ws_size,
                              hipStream_t stream)
{
    (void)in_sizes; (void)n_in; (void)out_size; (void)ws_size;
    const float* in    = (const float*)d_in[0];
    const float* cw    = (const float*)d_in[1];
    const float* gamma = (const float*)d_in[2];
    const float* beta  = (const float*)d_in[3];
    const float* Wih0  = (const float*)d_in[4];
    const float* Whh0  = (const float*)d_in[5];
    const float* b0    = (const float*)d_in[6];
    const float* Wih1  = (const float*)d_in[7];
    const float* Whh1  = (const float*)d_in[8];
    const float* b1    = (const float*)d_in[9];
    const float* Qw    = (const float*)d_in[10];
    const float* Qb    = (const float*)d_in[11];
    const float* Kw    = (const float*)d_in[12];
    const float* Kb    = (const float*)d_in[13];
    const float* Vw    = (const float*)d_in[14];
    const float* Vb    = (const float*)d_in[15];
    const float* mhw   = (const float*)d_in[16];
    const float* mhb   = (const float*)d_in[17];
    float* out = (float*)d_out;

    // workspace arena (floats). Same region map as before (hb/cb now unused).
    float* x0 = (float*)d_ws;                                   //  2,793,472 f
    float* G  = x0 + (size_t)RTOT*NF;                           // 22,347,776 f
    float* x1 = G  + (size_t)RTOT*2048;                         //  5,586,944 f
    float* x2 = x1 + (size_t)RTOT*512;                          //  5,586,944 f

    float* qbuf = G;
    float* kbuf = G + (size_t)RTOT*512;
    float* vbuf = G + (size_t)2*RTOT*512;
    float* P    = G + (size_t)3*RTOT*512;

    // ---- packed-buffer aliases (each placed in a region dead at time of use) ----
    unsigned short* x0p = (unsigned short*)x0;
    unsigned short* whh1_hi = (unsigned short*)x0;                         // after gemm1
    unsigned short* whh1_lo = whh1_hi + (size_t)524288;
    unsigned short* wih0_p  = (unsigned short*)x2;
    unsigned short* wih1_p  = wih0_p + (size_t)1048576;
    unsigned short* whh0_hi = wih1_p + (size_t)2097152;
    unsigned short* whh0_lo = whh0_hi + (size_t)524288;
    unsigned short* x1p  = (unsigned short*)x1;
    unsigned short* catp = (unsigned short*)x1;
    unsigned short* x2p = (unsigned short*)x2;
    float* gslack = P + (size_t)NH_*GRP*SP*PSTR;
    unsigned short* qw_p = (unsigned short*)gslack;
    unsigned short* kw_p = qw_p + (size_t)524288;
    unsigned short* vw_p = kw_p + (size_t)524288;
    unsigned short* mw_p = vw_p + (size_t)524288;

    #define PACKGRID(n) dim3(((n) + 255) / 256)

    // 1. conv+bn+relu+pool -> x0p (packed)
    conv_pool_k<<<dim3(22, B_), 256, 0, stream>>>(in, cw, gamma, beta, x0p);
    // 2. pack Wih0 (octet) into x2 region
    pack8_k<<<PACKGRID(65536), 256, 0, stream>>>(Wih0, wih0_p, 65536);
    // 3. layer-1 input gates: G = x0 @ Wih0^T + b0   (K=256)
    gemm_bf_k<0><<<dim3(16, 86), 256, 0, stream>>>(x0p, wih0_p, b0, G, RTOT, 2048, 256);
    // 4. pack Whh0 (x2 tail), Whh1 (x0 region, dead after gemm1), Wih1 (x2)
    pack4_k<<<PACKGRID(131072), 256, 0, stream>>>(Whh0, whh0_hi, whh0_lo, 131072);
    pack4_k<<<PACKGRID(131072), 256, 0, stream>>>(Whh1, whh1_hi, whh1_lo, 131072);
    pack8_k<<<PACKGRID(131072), 256, 0, stream>>>(Wih1, wih1_p, 131072);
    // 5. layer-1 scan -> x1p (sync-free, plain launch, 44 self-contained blocks)
    lstm_scan_k<<<dim3(22, 2), 256, 0, stream>>>(G, whh0_hi, whh0_lo, x1p);
    // 6. layer-2 input gates: G = x1 @ Wih1^T + b1   (K=512)
    gemm_bf_k<0><<<dim3(16, 86), 256, 0, stream>>>(x1p, wih1_p, b1, G, RTOT, 2048, 512);
    // 7. layer-2 scan -> x2p
    lstm_scan_k<<<dim3(22, 2), 256, 0, stream>>>(G, whh1_hi, whh1_lo, x2p);
    // 8. pack QKV/mh weights into G tail slack (G-as-gates dead)
    pack8_k<<<PACKGRID(32768), 256, 0, stream>>>(Qw,  qw_p, 32768);
    pack8_k<<<PACKGRID(32768), 256, 0, stream>>>(Kw,  kw_p, 32768);
    pack8_k<<<PACKGRID(32768), 256, 0, stream>>>(Vw,  vw_p, 32768);
    pack8_k<<<PACKGRID(32768), 256, 0, stream>>>(mhw, mw_p, 32768);
    // 9. Q/K/V projections (fp32 outputs into G region)
    gemm_bf_k<0><<<dim3(4, 86), 256, 0, stream>>>(x2p, qw_p, Qb, qbuf, RTOT, 512, 512);
    gemm_bf_k<0><<<dim3(4, 86), 256, 0, stream>>>(x2p, kw_p, Kb, kbuf, RTOT, 512, 512);
    gemm_bf_k<0><<<dim3(4, 86), 256, 0, stream>>>(x2p, vw_p, Vb, vbuf, RTOT, 512, 512);
    // 10. attention in GRP-batch groups; pv writes catp (x1 region, packed)
    for (int g = 0; g < B_/GRP; ++g) {
        scores_k <<<dim3(36, GRP, NH_), 256, 0, stream>>>(qbuf, kbuf, P, g);
        softmax_k<<<dim3(NH_*GRP*SP/4), 256, 0, stream>>>(P);
        pv_k     <<<dim3(6, GRP, NH_), 256, 0, stream>>>(P, vbuf, catp, g);
    }
    // 11. final linear + relu
    gemm_bf_k<1><<<dim3(4, 86), 256, 0, stream>>>(catp, mw_p, mhb, out, RTOT, 512, 512);
    #undef PACKGRID
}

// Round 8
// 3096.513 us; speedup vs baseline: 1.2190x; 1.2190x over previous
//
#include <hip/hip_runtime.h>
#include <math.h>

// Problem constants
#define B_    32
#define CIN   4
#define SLEN  2048
#define NF    256
#define HD    256          // LSTM hidden per direction
#define SP    341          // post conv+pool sequence length
#define RTOT  (B_*SP)      // 10912 rows
#define NH_   8
#define DH_   64
#define GRP   4            // batches per attention group
#define PSTR  344          // padded P row stride (16B-aligned)
#define HS    (SP*HD)      // 87296: per-dir h elems

typedef __attribute__((ext_vector_type(8))) short short8;
typedef __attribute__((ext_vector_type(4))) float floatx4;
typedef __attribute__((ext_vector_type(4))) unsigned short ushortx4;
typedef __attribute__((ext_vector_type(8))) unsigned short ushort8;

__device__ __forceinline__ float sigmoidf_(float x) { return 1.0f / (1.0f + expf(-x)); }

__device__ __forceinline__ unsigned short f2bf(float x) {
    unsigned int u = __float_as_uint(x);
    unsigned int r = (u + 0x7FFF + ((u >> 16) & 1)) >> 16;   // RNE
    return (unsigned short)r;
}
__device__ __forceinline__ float bf2f(unsigned short b) {
    return __uint_as_float(((unsigned int)b) << 16);
}

// ---------------------------------------------------------------------------
// Packed bf16 hi/lo "octet" layout: for a row of K fp32 values, the packed row
// has 2K ushorts: octet o (elems 8o..8o+7) occupies ushorts [16o..16o+7]=hi,
// [16o+8..16o+15]=lo.  One K-step of 32 elems = 128 contiguous bytes.
// ---------------------------------------------------------------------------

// Kernel 1: Conv1d(4->256,k13,pad6)+BN+ReLU+MaxPool1d(6) -> x0 packed
__global__ __launch_bounds__(256)
void conv_pool_k(const float* __restrict__ in, const float* __restrict__ cw,
                 const float* __restrict__ gamma, const float* __restrict__ beta,
                 unsigned short* __restrict__ x0p)
{
    const int b  = blockIdx.y;
    const int s0 = blockIdx.x * 16;
    const int co = threadIdx.x;
    __shared__ float ins[CIN][16*6 + 12];
    for (int idx = threadIdx.x; idx < CIN*108; idx += 256) {
        int ci = idx / 108, o = idx % 108;
        int pos = 6*s0 - 6 + o;
        ins[ci][o] = (pos >= 0 && pos < SLEN) ? in[(b*CIN + ci)*SLEN + pos] : 0.0f;
    }
    float wreg[52];
    {
        const float4* wp = (const float4*)(cw + co*52);
        #pragma unroll
        for (int j4 = 0; j4 < 13; ++j4) {
            float4 w4 = wp[j4];
            wreg[j4*4+0]=w4.x; wreg[j4*4+1]=w4.y; wreg[j4*4+2]=w4.z; wreg[j4*4+3]=w4.w;
        }
    }
    const float scale = gamma[co] * (1.0f / sqrtf(1.0f + 1e-5f));
    const float shift = beta[co];
    __syncthreads();
    for (int si = 0; si < 16; ++si) {
        int s = s0 + si;
        if (s >= SP) break;
        float win[CIN][18];
        #pragma unroll
        for (int ci = 0; ci < CIN; ++ci)
            #pragma unroll
            for (int o = 0; o < 18; ++o)
                win[ci][o] = ins[ci][6*si + o];
        float m = -1e30f;
        #pragma unroll
        for (int p6 = 0; p6 < 6; ++p6) {
            float acc = 0.0f;
            #pragma unroll
            for (int ci = 0; ci < CIN; ++ci)
                #pragma unroll
                for (int kk = 0; kk < 13; ++kk)
                    acc += win[ci][p6+kk] * wreg[ci*13+kk];
            float val = acc * scale + shift;
            val = fmaxf(val, 0.0f);
            m = fmaxf(m, val);
        }
        unsigned short hb_ = f2bf(m);
        unsigned short lb_ = f2bf(m - bf2f(hb_));
        size_t rb = (size_t)(b*SP + s)*512 + (size_t)(co >> 3)*16 + (co & 7);
        x0p[rb]     = hb_;
        x0p[rb + 8] = lb_;
    }
}

// Kernel 2a: fp32 -> separate hi/lo pack (for lstm Whh, layout unchanged)
__global__ __launch_bounds__(256)
void pack4_k(const float* __restrict__ W, unsigned short* __restrict__ hi,
             unsigned short* __restrict__ lo, int n4)
{
    int i = blockIdx.x * 256 + threadIdx.x;
    if (i >= n4) return;
    float4 x = *((const float4*)W + i);
    float v[4] = {x.x, x.y, x.z, x.w};
    ushortx4 h, l;
    #pragma unroll
    for (int e = 0; e < 4; ++e) {
        unsigned short hb = f2bf(v[e]);
        h[e] = hb;
        l[e] = f2bf(v[e] - bf2f(hb));
    }
    *((ushortx4*)hi + i) = h;
    *((ushortx4*)lo + i) = l;
}

// Kernel 2b: fp32 -> interleaved octet pack (8 elems/thread)
__global__ __launch_bounds__(256)
void pack8_k(const float* __restrict__ W, unsigned short* __restrict__ O, int n8)
{
    int i = blockIdx.x * 256 + threadIdx.x;
    if (i >= n8) return;
    const float4* wp = (const float4*)W + (size_t)i*2;
    float4 a = wp[0], b = wp[1];
    float v[8] = {a.x,a.y,a.z,a.w,b.x,b.y,b.z,b.w};
    ushort8 h, l;
    #pragma unroll
    for (int e = 0; e < 8; ++e) {
        unsigned short hb = f2bf(v[e]);
        h[e] = hb;
        l[e] = f2bf(v[e] - bf2f(hb));
    }
    *(ushort8*)(O + (size_t)i*16)     = h;
    *(ushort8*)(O + (size_t)i*16 + 8) = l;
}

// ---------------------------------------------------------------------------
// Kernel 3: split-bf16 MFMA GEMM, operands in packed octet layout.
// (unchanged from round 3)
// ---------------------------------------------------------------------------
template<int RELU>
__global__ __launch_bounds__(256)
void gemm_bf_k(const unsigned short* __restrict__ Ap, const unsigned short* __restrict__ Bp,
               const float* __restrict__ bias, float* __restrict__ C,
               int M, int N, int K)
{
    const int n0 = blockIdx.x * 128;
    const int m0 = blockIdx.y * 128;
    const int tid = threadIdx.x;
    const int lane = tid & 63;
    const int w = tid >> 6;
    const int wm = w >> 1, wn = w & 1;
    const int ln15 = lane & 15, lq = lane >> 4;
    const int l8 = lane >> 3, lj = lane & 7;
    const size_t rstr = 2*(size_t)K;

    __shared__ unsigned short As[128*64];
    __shared__ unsigned short Bs[128*64];

    floatx4 acc[4][4];
    #pragma unroll
    for (int i = 0; i < 4; ++i)
        #pragma unroll
        for (int j = 0; j < 4; ++j) acc[i][j] = (floatx4){0.f, 0.f, 0.f, 0.f};

    int rloc[4];
    #pragma unroll
    for (int c = 0; c < 4; ++c) rloc[c] = w*32 + c*8 + l8;
    const int spos = lj ^ (l8 & 7);

    for (int k0 = 0; k0 < K; k0 += 32) {
        short8 va[4], vb[4];
        #pragma unroll
        for (int c = 0; c < 4; ++c) {
            int gra = m0 + rloc[c]; if (gra >= M) gra = M - 1;
            va[c] = *(const short8*)(Ap + (size_t)gra*rstr + k0*2 + lj*8);
            vb[c] = *(const short8*)(Bp + (size_t)(n0 + rloc[c])*rstr + k0*2 + lj*8);
        }
        __syncthreads();
        #pragma unroll
        for (int c = 0; c < 4; ++c) {
            *(short8*)&As[rloc[c]*64 + spos*8] = va[c];
            *(short8*)&Bs[rloc[c]*64 + spos*8] = vb[c];
        }
        __syncthreads();

        short8 fa_h[4], fa_l[4], fb_h[4], fb_l[4];
        #pragma unroll
        for (int mt = 0; mt < 4; ++mt) {
            const int lr = wm*64 + mt*16 + ln15;
            fa_h[mt] = *(const short8*)&As[lr*64 + (((lq*2  ) ^ (lr&7))*8)];
            fa_l[mt] = *(const short8*)&As[lr*64 + (((lq*2+1) ^ (lr&7))*8)];
        }
        #pragma unroll
        for (int nt = 0; nt < 4; ++nt) {
            const int lr = wn*64 + nt*16 + ln15;
            fb_h[nt] = *(const short8*)&Bs[lr*64 + (((lq*2  ) ^ (lr&7))*8)];
            fb_l[nt] = *(const short8*)&Bs[lr*64 + (((lq*2+1) ^ (lr&7))*8)];
        }
        #pragma unroll
        for (int mt = 0; mt < 4; ++mt)
            #pragma unroll
            for (int nt = 0; nt < 4; ++nt) {
                acc[mt][nt] = __builtin_amdgcn_mfma_f32_16x16x32_bf16(fa_l[mt], fb_h[nt], acc[mt][nt], 0, 0, 0);
                acc[mt][nt] = __builtin_amdgcn_mfma_f32_16x16x32_bf16(fa_h[mt], fb_l[nt], acc[mt][nt], 0, 0, 0);
                acc[mt][nt] = __builtin_amdgcn_mfma_f32_16x16x32_bf16(fa_h[mt], fb_h[nt], acc[mt][nt], 0, 0, 0);
            }
    }

    #pragma unroll
    for (int nt = 0; nt < 4; ++nt) {
        const int n = n0 + wn*64 + nt*16 + ln15;
        const float bv = bias[n];
        #pragma unroll
        for (int mt = 0; mt < 4; ++mt) {
            const int mbase = m0 + wm*64 + mt*16 + lq*4;
            #pragma unroll
            for (int r = 0; r < 4; ++r) {
                int m = mbase + r;
                if (m < M) {
                    float val = acc[mt][nt][r] + bv;
                    if (RELU) val = fmaxf(val, 0.0f);
                    C[(size_t)m*N + n] = val;
                }
            }
        }
    }
}

// ---------------------------------------------------------------------------
// Kernel 3b: SYNC-FREE LSTM scan, v3 (low-VGPR, 16-wave blocks).
// Row-local recurrence: block owns 16 rows x ALL 256 h-cols, one dir.
// 1024 threads = 16 waves; wave jj owns j in [jj*16,(jj+1)*16) x 4 gates:
// acc[4] (one per gate), B rows g*256+jj*16+ln15.  Epilogue lane-local:
// cell (row=lq*4+r, j=jj*16+ln15) gates = acc[0..3][r].  4 waves/SIMD for
// latency hiding; ~100 VGPR.  h: LDS dbuf [2][16][256], XOR-chunk swizzle.
// c in registers.  Grid (22,2), plain launch, __syncthreads only.
// ---------------------------------------------------------------------------
__global__ __launch_bounds__(1024)
void lstm_scan_k(const float* __restrict__ G,              // [32*341][2048]
                 const unsigned short* __restrict__ Whi,   // [2][1024][256]
                 const unsigned short* __restrict__ Wlo,
                 unsigned short* __restrict__ x_out)       // [32*341] packed rows of 512
{
    const int m0 = blockIdx.x * 16;
    const int d  = blockIdx.y;
    const int tid = threadIdx.x;
    const int jj = tid >> 6;              // wave index = j-sixteenth
    const int lane = tid & 63;
    const int ln15 = lane & 15, lq = lane >> 4;

    __shared__ float hbuf[2][16][256];
    for (int i = tid; i < 2*16*256; i += 1024)
        ((float*)hbuf)[i] = 0.0f;
    __syncthreads();

    const unsigned short* WhiD = Whi + (size_t)d*1024*256;
    const unsigned short* WloD = Wlo + (size_t)d*1024*256;

    int brow[4];                          // B row per gate
    #pragma unroll
    for (int g = 0; g < 4; ++g) brow[g] = g*256 + jj*16 + ln15;

    const int j = jj*16 + ln15;           // this lane's j column
    float creg[4] = {0.f, 0.f, 0.f, 0.f}; // c-state for rows lq*4+r

    for (int s = 0; s < B_; ++s) {
        const int t_in = d ? (B_ - 1 - s) : s;
        const int rbuf = s & 1, wbuf = (s + 1) & 1;

        floatx4 acc[4];
        #pragma unroll
        for (int g = 0; g < 4; ++g) acc[g] = (floatx4){0.f, 0.f, 0.f, 0.f};

        if (s > 0) {
            #pragma unroll
            for (int kk = 0; kk < 8; ++kk) {
                // A-frag: row=ln15, k=kk*32+lq*8+e (swizzled chunk)
                const int cs = (kk*4 + lq) ^ (ln15 & 7);
                const float* hp = &hbuf[rbuf][ln15][cs*8];
                float4 v0 = *(const float4*)hp;
                float4 v1 = *(const float4*)(hp + 4);
                float vv[8] = {v0.x, v0.y, v0.z, v0.w, v1.x, v1.y, v1.z, v1.w};
                short8 ahi, alo;
                #pragma unroll
                for (int e = 0; e < 8; ++e) {
                    unsigned short hb16 = f2bf(vv[e]);
                    ahi[e] = (short)hb16;
                    alo[e] = (short)f2bf(vv[e] - bf2f(hb16));
                }
                const int ko = kk*32 + lq*8;
                #pragma unroll
                for (int g = 0; g < 4; ++g) {
                    short8 bhi = *(const short8*)(WhiD + (size_t)brow[g]*HD + ko);
                    short8 blo = *(const short8*)(WloD + (size_t)brow[g]*HD + ko);
                    acc[g] = __builtin_amdgcn_mfma_f32_16x16x32_bf16(alo, bhi, acc[g], 0, 0, 0);
                    acc[g] = __builtin_amdgcn_mfma_f32_16x16x32_bf16(ahi, blo, acc[g], 0, 0, 0);
                    acc[g] = __builtin_amdgcn_mfma_f32_16x16x32_bf16(ahi, bhi, acc[g], 0, 0, 0);
                }
            }
        }

        // epilogue: lane-local gates for rows lq*4+r
        #pragma unroll
        for (int r = 0; r < 4; ++r) {
            const int row = lq*4 + r;
            const int em  = m0 + row;
            if (em < SP) {
                const size_t gbase = ((size_t)t_in*SP + em)*2048 + (size_t)d*1024 + j;
                float gi = acc[0][r] + G[gbase];
                float gf = acc[1][r] + G[gbase + 256];
                float gg = acc[2][r] + G[gbase + 512];
                float go = acc[3][r] + G[gbase + 768];
                float cn = sigmoidf_(gf)*creg[r] + sigmoidf_(gi)*tanhf(gg);
                creg[r] = cn;
                float hv = sigmoidf_(go)*tanhf(cn);
                // h -> LDS (swizzled chunk)
                const int cs = (j >> 3) ^ (row & 7);
                hbuf[wbuf][row][cs*8 + (j & 7)] = hv;
                // packed x_out
                const int colg = d*HD + j;
                size_t xb = ((size_t)t_in*SP + em)*1024 + (size_t)(colg >> 3)*16 + (colg & 7);
                unsigned short hb16 = f2bf(hv);
                x_out[xb]     = hb16;
                x_out[xb + 8] = f2bf(hv - bf2f(hb16));
            }
        }
        __syncthreads();   // h[wbuf] visible; h[rbuf] reads complete
    }
}

// ---------------------------------------------------------------------------
// Kernel 4a: scores tile (64x64), RPE analytic.
// ---------------------------------------------------------------------------
__global__ __launch_bounds__(256)
void scores_k(const float* __restrict__ q, const float* __restrict__ k,
              float* __restrict__ P, int g)
{
    const int h = blockIdx.z, bl = blockIdx.y, bg = g*GRP + bl;
    const int q0 = (blockIdx.x / 6) * 64;
    const int k0 = (blockIdx.x % 6) * 64;
    const int tid = threadIdx.x;
    __shared__ float qs[64][68];
    __shared__ float ks[64][68];
    {
        int jr = tid >> 2, c16 = (tid & 3) * 16;
        int qq = q0 + jr; if (qq > SP-1) qq = SP-1;
        int kr = k0 + jr; if (kr > SP-1) kr = SP-1;
        const float* qp = &q[((size_t)bg*SP + qq)*512 + h*64 + c16];
        const float* kp = &k[((size_t)bg*SP + kr)*512 + h*64 + c16];
        #pragma unroll
        for (int u = 0; u < 4; ++u) {
            *(float4*)&qs[jr][c16 + u*4] = *(const float4*)(qp + u*4);
            *(float4*)&ks[jr][c16 + u*4] = *(const float4*)(kp + u*4);
        }
    }
    __syncthreads();
    const int tx = tid & 15, ty = tid >> 4;
    float acc[4][4];
    #pragma unroll
    for (int i = 0; i < 4; ++i)
        #pragma unroll
        for (int j = 0; j < 4; ++j) acc[i][j] = 0.0f;
    for (int d4 = 0; d4 < 64; d4 += 4) {
        float4 a[4], b[4];
        #pragma unroll
        for (int i = 0; i < 4; ++i) a[i] = *(const float4*)&qs[ty + 16*i][d4];
        #pragma unroll
        for (int j = 0; j < 4; ++j) b[j] = *(const float4*)&ks[tx + 16*j][d4];
        #pragma unroll
        for (int i = 0; i < 4; ++i)
            #pragma unroll
            for (int j = 0; j < 4; ++j)
                acc[i][j] += a[i].x*b[j].x + a[i].y*b[j].y + a[i].z*b[j].z + a[i].w*b[j].w;
    }
    #pragma unroll
    for (int i = 0; i < 4; ++i) {
        int qq = q0 + ty + 16*i;
        if (qq >= SP) continue;
        int r0 = 6*qq - 1; if (r0 < 0) r0 = 0;
        int r1 = 6*qq + 7; if (r1 > SLEN-1) r1 = SLEN-1;
        size_t rowb = ((size_t)(h*GRP + bl)*SP + qq) * PSTR;
        #pragma unroll
        for (int j = 0; j < 4; ++j) {
            int kk = k0 + tx + 16*j;
            if (kk >= SP) continue;
            int c0 = 6*kk - 1; if (c0 < 0) c0 = 0;
            int c1 = 6*kk + 7;
            int dd1 = c1 - r0; if (dd1 < 0) dd1 = -dd1;
            int dd2 = r1 - c0; if (dd2 < 0) dd2 = -dd2;
            int den = dd1 > dd2 ? dd1 : dd2;
            P[rowb + kk] = (acc[i][j] * 0.125f) * 2047.0f / (float)den;
        }
    }
}

// ---------------------------------------------------------------------------
// Kernel 4b: row softmax in place.
// ---------------------------------------------------------------------------
__global__ __launch_bounds__(256)
void softmax_k(float* __restrict__ P)
{
    const int tid = threadIdx.x;
    const int row = blockIdx.x * 4 + (tid >> 6);
    const int lane = tid & 63;
    float* rp = P + (size_t)row * PSTR;
    float v[6];
    float m = -1e30f;
    #pragma unroll
    for (int i = 0; i < 6; ++i) {
        int col = lane + 64*i;
        v[i] = (col < SP) ? rp[col] : -1e30f;
        m = fmaxf(m, v[i]);
    }
    #pragma unroll
    for (int o = 1; o < 64; o <<= 1) m = fmaxf(m, __shfl_xor(m, o, 64));
    float s = 0.0f;
    #pragma unroll
    for (int i = 0; i < 6; ++i) {
        v[i] = expf(v[i] - m);
        s += v[i];
    }
    #pragma unroll
    for (int o = 1; o < 64; o <<= 1) s += __shfl_xor(s, o, 64);
    float inv = 1.0f / s;
    #pragma unroll
    for (int i = 0; i < 6; ++i) {
        int col = lane + 64*i;
        if (col < SP) rp[col] = v[i] * inv;
    }
}

// ---------------------------------------------------------------------------
// Kernel 4c: out = relu(P @ V), K=SP in 6x64 chunks. cat written PACKED.
// ---------------------------------------------------------------------------
__global__ __launch_bounds__(256)
void pv_k(const float* __restrict__ P, const float* __restrict__ v,
          unsigned short* __restrict__ catp, int g)
{
    const int h = blockIdx.z, bl = blockIdx.y, bg = g*GRP + bl;
    const int q0 = blockIdx.x * 64;
    const int tid = threadIdx.x;
    __shared__ float ps[64][68];
    __shared__ float vs[64][68];
    const int tx = tid & 15, ty = tid >> 4;
    float acc[4][4];
    #pragma unroll
    for (int i = 0; i < 4; ++i)
        #pragma unroll
        for (int j = 0; j < 4; ++j) acc[i][j] = 0.0f;

    for (int kc = 0; kc < 6; ++kc) {
        const int kk0 = kc * 64;
        {
            int jr = tid >> 2, c16 = (tid & 3) * 16;
            int qq = q0 + jr; if (qq > SP-1) qq = SP-1;
            const float* pp = P + ((size_t)(h*GRP + bl)*SP + qq)*PSTR + kk0 + c16;
            #pragma unroll
            for (int u = 0; u < 4; ++u) {
                float4 w = *(const float4*)(pp + u*4);
                int klb = c16 + u*4;
                float vals[4] = {w.x, w.y, w.z, w.w};
                #pragma unroll
                for (int e = 0; e < 4; ++e)
                    ps[klb + e][jr] = (kk0 + klb + e < SP) ? vals[e] : 0.0f;
            }
        }
        {
            int jr = tid >> 2, c16 = (tid & 3) * 16;
            int kr = kk0 + jr; if (kr > SP-1) kr = SP-1;
            const float* vp = &v[((size_t)bg*SP + kr)*512 + h*64 + c16];
            #pragma unroll
            for (int u = 0; u < 4; ++u)
                *(float4*)&vs[jr][c16 + u*4] = *(const float4*)(vp + u*4);
        }
        __syncthreads();
        for (int kk = 0; kk < 64; ++kk) {
            float4 a4 = *(const float4*)&ps[kk][ty*4];
            float4 b4 = *(const float4*)&vs[kk][tx*4];
            float av[4] = {a4.x, a4.y, a4.z, a4.w};
            float bv[4] = {b4.x, b4.y, b4.z, b4.w};
            #pragma unroll
            for (int i = 0; i < 4; ++i)
                #pragma unroll
                for (int j = 0; j < 4; ++j)
                    acc[i][j] += av[i] * bv[j];
        }
        __syncthreads();
    }
    #pragma unroll
    for (int i = 0; i < 4; ++i) {
        int qq = q0 + ty*4 + i;
        if (qq >= SP) continue;
        float r[4];
        r[0] = fmaxf(acc[i][0], 0.0f);
        r[1] = fmaxf(acc[i][1], 0.0f);
        r[2] = fmaxf(acc[i][2], 0.0f);
        r[3] = fmaxf(acc[i][3], 0.0f);
        const int colg = h*64 + tx*4;
        size_t xb = ((size_t)bg*SP + qq)*1024 + (size_t)(colg >> 3)*16 + (colg & 7);
        ushortx4 xh, xl;
        #pragma unroll
        for (int e = 0; e < 4; ++e) {
            unsigned short hb16 = f2bf(r[e]);
            xh[e] = hb16;
            xl[e] = f2bf(r[e] - bf2f(hb16));
        }
        *(ushortx4*)&catp[xb]     = xh;
        *(ushortx4*)&catp[xb + 8] = xl;
    }
}

// ---------------------------------------------------------------------------
extern "C" void kernel_launch(void* const* d_in, const int* in_sizes, int n_in,
                              void* d_out, int out_size, void* d_ws, size_t ws_size,
                              hipStream_t stream)
{
    (void)in_sizes; (void)n_in; (void)out_size; (void)ws_size;
    const float* in    = (const float*)d_in[0];
    const float* cw    = (const float*)d_in[1];
    const float* gamma = (const float*)d_in[2];
    const float* beta  = (const float*)d_in[3];
    const float* Wih0  = (const float*)d_in[4];
    const float* Whh0  = (const float*)d_in[5];
    const float* b0    = (const float*)d_in[6];
    const float* Wih1  = (const float*)d_in[7];
    const float* Whh1  = (const float*)d_in[8];
    const float* b1    = (const float*)d_in[9];
    const float* Qw    = (const float*)d_in[10];
    const float* Qb    = (const float*)d_in[11];
    const float* Kw    = (const float*)d_in[12];
    const float* Kb    = (const float*)d_in[13];
    const float* Vw    = (const float*)d_in[14];
    const float* Vb    = (const float*)d_in[15];
    const float* mhw   = (const float*)d_in[16];
    const float* mhb   = (const float*)d_in[17];
    float* out = (float*)d_out;

    // workspace arena (floats). Same region map as before (hb/cb unused now).
    float* x0 = (float*)d_ws;                                   //  2,793,472 f
    float* G  = x0 + (size_t)RTOT*NF;                           // 22,347,776 f
    float* x1 = G  + (size_t)RTOT*2048;                         //  5,586,944 f
    float* x2 = x1 + (size_t)RTOT*512;                          //  5,586,944 f

    float* qbuf = G;
    float* kbuf = G + (size_t)RTOT*512;
    float* vbuf = G + (size_t)2*RTOT*512;
    float* P    = G + (size_t)3*RTOT*512;

    // ---- packed-buffer aliases (each placed in a region dead at time of use) ----
    unsigned short* x0p = (unsigned short*)x0;
    unsigned short* whh1_hi = (unsigned short*)x0;                         // after gemm1
    unsigned short* whh1_lo = whh1_hi + (size_t)524288;
    unsigned short* wih0_p  = (unsigned short*)x2;
    unsigned short* wih1_p  = wih0_p + (size_t)1048576;
    unsigned short* whh0_hi = wih1_p + (size_t)2097152;
    unsigned short* whh0_lo = whh0_hi + (size_t)524288;
    unsigned short* x1p  = (unsigned short*)x1;
    unsigned short* catp = (unsigned short*)x1;
    unsigned short* x2p = (unsigned short*)x2;
    float* gslack = P + (size_t)NH_*GRP*SP*PSTR;
    unsigned short* qw_p = (unsigned short*)gslack;
    unsigned short* kw_p = qw_p + (size_t)524288;
    unsigned short* vw_p = kw_p + (size_t)524288;
    unsigned short* mw_p = vw_p + (size_t)524288;

    #define PACKGRID(n) dim3(((n) + 255) / 256)

    // 1. conv+bn+relu+pool -> x0p (packed)
    conv_pool_k<<<dim3(22, B_), 256, 0, stream>>>(in, cw, gamma, beta, x0p);
    // 2. pack Wih0 (octet) into x2 region
    pack8_k<<<PACKGRID(65536), 256, 0, stream>>>(Wih0, wih0_p, 65536);
    // 3. layer-1 input gates: G = x0 @ Wih0^T + b0   (K=256)
    gemm_bf_k<0><<<dim3(16, 86), 256, 0, stream>>>(x0p, wih0_p, b0, G, RTOT, 2048, 256);
    // 4. pack Whh0 (x2 tail), Whh1 (x0 region, dead after gemm1), Wih1 (x2)
    pack4_k<<<PACKGRID(131072), 256, 0, stream>>>(Whh0, whh0_hi, whh0_lo, 131072);
    pack4_k<<<PACKGRID(131072), 256, 0, stream>>>(Whh1, whh1_hi, whh1_lo, 131072);
    pack8_k<<<PACKGRID(131072), 256, 0, stream>>>(Wih1, wih1_p, 131072);
    // 5. layer-1 scan -> x1p (sync-free, 16-wave blocks)
    lstm_scan_k<<<dim3(22, 2), 1024, 0, stream>>>(G, whh0_hi, whh0_lo, x1p);
    // 6. layer-2 input gates: G = x1 @ Wih1^T + b1   (K=512)
    gemm_bf_k<0><<<dim3(16, 86), 256, 0, stream>>>(x1p, wih1_p, b1, G, RTOT, 2048, 512);
    // 7. layer-2 scan -> x2p
    lstm_scan_k<<<dim3(22, 2), 1024, 0, stream>>>(G, whh1_hi, whh1_lo, x2p);
    // 8. pack QKV/mh weights into G tail slack (G-as-gates dead)
    pack8_k<<<PACKGRID(32768), 256, 0, stream>>>(Qw,  qw_p, 32768);
    pack8_k<<<PACKGRID(32768), 256, 0, stream>>>(Kw,  kw_p, 32768);
    pack8_k<<<PACKGRID(32768), 256, 0, stream>>>(Vw,  vw_p, 32768);
    pack8_k<<<PACKGRID(32768), 256, 0, stream>>>(mhw, mw_p, 32768);
    // 9. Q/K/V projections (fp32 outputs into G region)
    gemm_bf_k<0><<<dim3(4, 86), 256, 0, stream>>>(x2p, qw_p, Qb, qbuf, RTOT, 512, 512);
    gemm_bf_k<0><<<dim3(4, 86), 256, 0, stream>>>(x2p, kw_p, Kb, kbuf, RTOT, 512, 512);
    gemm_bf_k<0><<<dim3(4, 86), 256, 0, stream>>>(x2p, vw_p, Vb, vbuf, RTOT, 512, 512);
    // 10. attention in GRP-batch groups; pv writes catp (x1 region, packed)
    for (int g = 0; g < B_/GRP; ++g) {
        scores_k <<<dim3(36, GRP, NH_), 256, 0, stream>>>(qbuf, kbuf, P, g);
        softmax_k<<<dim3(NH_*GRP*SP/4), 256, 0, stream>>>(P);
        pv_k     <<<dim3(6, GRP, NH_), 256, 0, stream>>>(P, vbuf, catp, g);
    }
    // 11. final linear + relu
    gemm_bf_k<1><<<dim3(4, 86), 256, 0, stream>>>(catp, mw_p, mhb, out, RTOT, 512, 512);
    #undef PACKGRID
}

// Round 9
// 1698.883 us; speedup vs baseline: 2.2218x; 1.8227x over previous
//
#include <hip/hip_runtime.h>
#include <math.h>

// Problem constants
#define B_    32
#define CIN   4
#define SLEN  2048
#define NF    256
#define HD    256          // LSTM hidden per direction
#define SP    341          // post conv+pool sequence length
#define RTOT  (B_*SP)      // 10912 rows
#define NH_   8
#define DH_   64
#define GRP   4            // batches per attention group
#define PSTR  344          // (legacy) padded P row stride
#define HS    (SP*HD)      // 87296: per-dir h elems
#define PKS   768          // packed P / vT row stride in ushorts (384 elems)

typedef __attribute__((ext_vector_type(8))) short short8;
typedef __attribute__((ext_vector_type(4))) float floatx4;
typedef __attribute__((ext_vector_type(4))) unsigned short ushortx4;
typedef __attribute__((ext_vector_type(8))) unsigned short ushort8;

__device__ __forceinline__ float sigmoidf_(float x) { return 1.0f / (1.0f + expf(-x)); }

__device__ __forceinline__ unsigned short f2bf(float x) {
    unsigned int u = __float_as_uint(x);
    unsigned int r = (u + 0x7FFF + ((u >> 16) & 1)) >> 16;   // RNE
    return (unsigned short)r;
}
__device__ __forceinline__ float bf2f(unsigned short b) {
    return __uint_as_float(((unsigned int)b) << 16);
}

// ---- LLC-coherent (Infinity Cache) access helpers: sc0 sc1 bypass L1/L2 ----
__device__ __forceinline__ void store_f4_llc(float* p, floatx4 v)
{
    asm volatile("global_store_dwordx4 %0, %1, off sc0 sc1" :: "v"(p), "v"(v) : "memory");
}
__device__ __forceinline__ unsigned load_u32_llc(const unsigned* p)
{
    unsigned r;
    asm volatile("global_load_dword %0, %1, off sc0 sc1\n\ts_waitcnt vmcnt(0)"
                 : "=v"(r) : "v"(p) : "memory");
    return r;
}
// 16 x dwordx4 from one base; single trailing waitcnt INSIDE the asm.
__device__ __forceinline__ void load_h16_llc(const float* p, floatx4* r)
{
    asm volatile(
        "global_load_dwordx4 %0, %16, off sc0 sc1\n\t"
        "global_load_dwordx4 %1, %16, off offset:16 sc0 sc1\n\t"
        "global_load_dwordx4 %2, %16, off offset:128 sc0 sc1\n\t"
        "global_load_dwordx4 %3, %16, off offset:144 sc0 sc1\n\t"
        "global_load_dwordx4 %4, %16, off offset:256 sc0 sc1\n\t"
        "global_load_dwordx4 %5, %16, off offset:272 sc0 sc1\n\t"
        "global_load_dwordx4 %6, %16, off offset:384 sc0 sc1\n\t"
        "global_load_dwordx4 %7, %16, off offset:400 sc0 sc1\n\t"
        "global_load_dwordx4 %8, %16, off offset:512 sc0 sc1\n\t"
        "global_load_dwordx4 %9, %16, off offset:528 sc0 sc1\n\t"
        "global_load_dwordx4 %10, %16, off offset:640 sc0 sc1\n\t"
        "global_load_dwordx4 %11, %16, off offset:656 sc0 sc1\n\t"
        "global_load_dwordx4 %12, %16, off offset:768 sc0 sc1\n\t"
        "global_load_dwordx4 %13, %16, off offset:784 sc0 sc1\n\t"
        "global_load_dwordx4 %14, %16, off offset:896 sc0 sc1\n\t"
        "global_load_dwordx4 %15, %16, off offset:912 sc0 sc1\n\t"
        "s_waitcnt vmcnt(0)"
        : "=&v"(r[0]), "=&v"(r[1]), "=&v"(r[2]), "=&v"(r[3]),
          "=&v"(r[4]), "=&v"(r[5]), "=&v"(r[6]), "=&v"(r[7]),
          "=&v"(r[8]), "=&v"(r[9]), "=&v"(r[10]), "=&v"(r[11]),
          "=&v"(r[12]), "=&v"(r[13]), "=&v"(r[14]), "=&v"(r[15])
        : "v"(p)
        : "memory");
}

// ---------------------------------------------------------------------------
// Packed bf16 hi/lo "octet" layout: row of K fp32 -> 2K ushorts; octet o:
// [16o..16o+7]=hi, [16o+8..16o+15]=lo.  K-step 32 = 128 contiguous bytes.
// ---------------------------------------------------------------------------

// Kernel 1: Conv1d(4->256,k13,pad6)+BN+ReLU+MaxPool1d(6) -> x0 packed
__global__ __launch_bounds__(256)
void conv_pool_k(const float* __restrict__ in, const float* __restrict__ cw,
                 const float* __restrict__ gamma, const float* __restrict__ beta,
                 unsigned short* __restrict__ x0p)
{
    const int b  = blockIdx.y;
    const int s0 = blockIdx.x * 16;
    const int co = threadIdx.x;
    __shared__ float ins[CIN][16*6 + 12];
    for (int idx = threadIdx.x; idx < CIN*108; idx += 256) {
        int ci = idx / 108, o = idx % 108;
        int pos = 6*s0 - 6 + o;
        ins[ci][o] = (pos >= 0 && pos < SLEN) ? in[(b*CIN + ci)*SLEN + pos] : 0.0f;
    }
    float wreg[52];
    {
        const float4* wp = (const float4*)(cw + co*52);
        #pragma unroll
        for (int j4 = 0; j4 < 13; ++j4) {
            float4 w4 = wp[j4];
            wreg[j4*4+0]=w4.x; wreg[j4*4+1]=w4.y; wreg[j4*4+2]=w4.z; wreg[j4*4+3]=w4.w;
        }
    }
    const float scale = gamma[co] * (1.0f / sqrtf(1.0f + 1e-5f));
    const float shift = beta[co];
    __syncthreads();
    for (int si = 0; si < 16; ++si) {
        int s = s0 + si;
        if (s >= SP) break;
        float win[CIN][18];
        #pragma unroll
        for (int ci = 0; ci < CIN; ++ci)
            #pragma unroll
            for (int o = 0; o < 18; ++o)
                win[ci][o] = ins[ci][6*si + o];
        float m = -1e30f;
        #pragma unroll
        for (int p6 = 0; p6 < 6; ++p6) {
            float acc = 0.0f;
            #pragma unroll
            for (int ci = 0; ci < CIN; ++ci)
                #pragma unroll
                for (int kk = 0; kk < 13; ++kk)
                    acc += win[ci][p6+kk] * wreg[ci*13+kk];
            float val = acc * scale + shift;
            val = fmaxf(val, 0.0f);
            m = fmaxf(m, val);
        }
        unsigned short hb_ = f2bf(m);
        unsigned short lb_ = f2bf(m - bf2f(hb_));
        size_t rb = (size_t)(b*SP + s)*512 + (size_t)(co >> 3)*16 + (co & 7);
        x0p[rb]     = hb_;
        x0p[rb + 8] = lb_;
    }
}

// Kernel 2a: fp32 -> separate hi/lo pack (for lstm Whh)
__global__ __launch_bounds__(256)
void pack4_k(const float* __restrict__ W, unsigned short* __restrict__ hi,
             unsigned short* __restrict__ lo, int n4)
{
    int i = blockIdx.x * 256 + threadIdx.x;
    if (i >= n4) return;
    float4 x = *((const float4*)W + i);
    float v[4] = {x.x, x.y, x.z, x.w};
    ushortx4 h, l;
    #pragma unroll
    for (int e = 0; e < 4; ++e) {
        unsigned short hb = f2bf(v[e]);
        h[e] = hb;
        l[e] = f2bf(v[e] - bf2f(hb));
    }
    *((ushortx4*)hi + i) = h;
    *((ushortx4*)lo + i) = l;
}

// Kernel 2b: fp32 -> interleaved octet pack (8 elems/thread)
__global__ __launch_bounds__(256)
void pack8_k(const float* __restrict__ W, unsigned short* __restrict__ O, int n8)
{
    int i = blockIdx.x * 256 + threadIdx.x;
    if (i >= n8) return;
    const float4* wp = (const float4*)W + (size_t)i*2;
    float4 a = wp[0], b = wp[1];
    float v[8] = {a.x,a.y,a.z,a.w,b.x,b.y,b.z,b.w};
    ushort8 h, l;
    #pragma unroll
    for (int e = 0; e < 8; ++e) {
        unsigned short hb = f2bf(v[e]);
        h[e] = hb;
        l[e] = f2bf(v[e] - bf2f(hb));
    }
    *(ushort8*)(O + (size_t)i*16)     = h;
    *(ushort8*)(O + (size_t)i*16 + 8) = l;
}

// ---------------------------------------------------------------------------
// Kernel 3: split-bf16 MFMA GEMM, packed octet operands (unchanged).
// ---------------------------------------------------------------------------
template<int RELU>
__global__ __launch_bounds__(256)
void gemm_bf_k(const unsigned short* __restrict__ Ap, const unsigned short* __restrict__ Bp,
               const float* __restrict__ bias, float* __restrict__ C,
               int M, int N, int K)
{
    const int n0 = blockIdx.x * 128;
    const int m0 = blockIdx.y * 128;
    const int tid = threadIdx.x;
    const int lane = tid & 63;
    const int w = tid >> 6;
    const int wm = w >> 1, wn = w & 1;
    const int ln15 = lane & 15, lq = lane >> 4;
    const int l8 = lane >> 3, lj = lane & 7;
    const size_t rstr = 2*(size_t)K;

    __shared__ unsigned short As[128*64];
    __shared__ unsigned short Bs[128*64];

    floatx4 acc[4][4];
    #pragma unroll
    for (int i = 0; i < 4; ++i)
        #pragma unroll
        for (int j = 0; j < 4; ++j) acc[i][j] = (floatx4){0.f, 0.f, 0.f, 0.f};

    int rloc[4];
    #pragma unroll
    for (int c = 0; c < 4; ++c) rloc[c] = w*32 + c*8 + l8;
    const int spos = lj ^ (l8 & 7);

    for (int k0 = 0; k0 < K; k0 += 32) {
        short8 va[4], vb[4];
        #pragma unroll
        for (int c = 0; c < 4; ++c) {
            int gra = m0 + rloc[c]; if (gra >= M) gra = M - 1;
            va[c] = *(const short8*)(Ap + (size_t)gra*rstr + k0*2 + lj*8);
            vb[c] = *(const short8*)(Bp + (size_t)(n0 + rloc[c])*rstr + k0*2 + lj*8);
        }
        __syncthreads();
        #pragma unroll
        for (int c = 0; c < 4; ++c) {
            *(short8*)&As[rloc[c]*64 + spos*8] = va[c];
            *(short8*)&Bs[rloc[c]*64 + spos*8] = vb[c];
        }
        __syncthreads();

        short8 fa_h[4], fa_l[4], fb_h[4], fb_l[4];
        #pragma unroll
        for (int mt = 0; mt < 4; ++mt) {
            const int lr = wm*64 + mt*16 + ln15;
            fa_h[mt] = *(const short8*)&As[lr*64 + (((lq*2  ) ^ (lr&7))*8)];
            fa_l[mt] = *(const short8*)&As[lr*64 + (((lq*2+1) ^ (lr&7))*8)];
        }
        #pragma unroll
        for (int nt = 0; nt < 4; ++nt) {
            const int lr = wn*64 + nt*16 + ln15;
            fb_h[nt] = *(const short8*)&Bs[lr*64 + (((lq*2  ) ^ (lr&7))*8)];
            fb_l[nt] = *(const short8*)&Bs[lr*64 + (((lq*2+1) ^ (lr&7))*8)];
        }
        #pragma unroll
        for (int mt = 0; mt < 4; ++mt)
            #pragma unroll
            for (int nt = 0; nt < 4; ++nt) {
                acc[mt][nt] = __builtin_amdgcn_mfma_f32_16x16x32_bf16(fa_l[mt], fb_h[nt], acc[mt][nt], 0, 0, 0);
                acc[mt][nt] = __builtin_amdgcn_mfma_f32_16x16x32_bf16(fa_h[mt], fb_l[nt], acc[mt][nt], 0, 0, 0);
                acc[mt][nt] = __builtin_amdgcn_mfma_f32_16x16x32_bf16(fa_h[mt], fb_h[nt], acc[mt][nt], 0, 0, 0);
            }
    }

    #pragma unroll
    for (int nt = 0; nt < 4; ++nt) {
        const int n = n0 + wn*64 + nt*16 + ln15;
        const float bv = bias[n];
        #pragma unroll
        for (int mt = 0; mt < 4; ++mt) {
            const int mbase = m0 + wm*64 + mt*16 + lq*4;
            #pragma unroll
            for (int r = 0; r < 4; ++r) {
                int m = mbase + r;
                if (m < M) {
                    float val = acc[mt][nt][r] + bv;
                    if (RELU) val = fmaxf(val, 0.0f);
                    C[(size_t)m*N + n] = val;
                }
            }
        }
    }
}

// ---------------------------------------------------------------------------
// Kernel 3v: same GEMM body, epilogue writes TRANSPOSED packed output:
// vT[(bg*512 + n)][sp packed octet], bg = m/341, sp = m%341, stride PKS.
// vT must be zero-memset first (pad cols 341..383 stay 0).
// ---------------------------------------------------------------------------
__global__ __launch_bounds__(256)
void gemm_vT_k(const unsigned short* __restrict__ Ap, const unsigned short* __restrict__ Bp,
               const float* __restrict__ bias, unsigned short* __restrict__ vT,
               int M, int N, int K)
{
    const int n0 = blockIdx.x * 128;
    const int m0 = blockIdx.y * 128;
    const int tid = threadIdx.x;
    const int lane = tid & 63;
    const int w = tid >> 6;
    const int wm = w >> 1, wn = w & 1;
    const int ln15 = lane & 15, lq = lane >> 4;
    const int l8 = lane >> 3, lj = lane & 7;
    const size_t rstr = 2*(size_t)K;

    __shared__ unsigned short As[128*64];
    __shared__ unsigned short Bs[128*64];

    floatx4 acc[4][4];
    #pragma unroll
    for (int i = 0; i < 4; ++i)
        #pragma unroll
        for (int j = 0; j < 4; ++j) acc[i][j] = (floatx4){0.f, 0.f, 0.f, 0.f};

    int rloc[4];
    #pragma unroll
    for (int c = 0; c < 4; ++c) rloc[c] = w*32 + c*8 + l8;
    const int spos = lj ^ (l8 & 7);

    for (int k0 = 0; k0 < K; k0 += 32) {
        short8 va[4], vb[4];
        #pragma unroll
        for (int c = 0; c < 4; ++c) {
            int gra = m0 + rloc[c]; if (gra >= M) gra = M - 1;
            va[c] = *(const short8*)(Ap + (size_t)gra*rstr + k0*2 + lj*8);
            vb[c] = *(const short8*)(Bp + (size_t)(n0 + rloc[c])*rstr + k0*2 + lj*8);
        }
        __syncthreads();
        #pragma unroll
        for (int c = 0; c < 4; ++c) {
            *(short8*)&As[rloc[c]*64 + spos*8] = va[c];
            *(short8*)&Bs[rloc[c]*64 + spos*8] = vb[c];
        }
        __syncthreads();

        short8 fa_h[4], fa_l[4], fb_h[4], fb_l[4];
        #pragma unroll
        for (int mt = 0; mt < 4; ++mt) {
            const int lr = wm*64 + mt*16 + ln15;
            fa_h[mt] = *(const short8*)&As[lr*64 + (((lq*2  ) ^ (lr&7))*8)];
            fa_l[mt] = *(const short8*)&As[lr*64 + (((lq*2+1) ^ (lr&7))*8)];
        }
        #pragma unroll
        for (int nt = 0; nt < 4; ++nt) {
            const int lr = wn*64 + nt*16 + ln15;
            fb_h[nt] = *(const short8*)&Bs[lr*64 + (((lq*2  ) ^ (lr&7))*8)];
            fb_l[nt] = *(const short8*)&Bs[lr*64 + (((lq*2+1) ^ (lr&7))*8)];
        }
        #pragma unroll
        for (int mt = 0; mt < 4; ++mt)
            #pragma unroll
            for (int nt = 0; nt < 4; ++nt) {
                acc[mt][nt] = __builtin_amdgcn_mfma_f32_16x16x32_bf16(fa_l[mt], fb_h[nt], acc[mt][nt], 0, 0, 0);
                acc[mt][nt] = __builtin_amdgcn_mfma_f32_16x16x32_bf16(fa_h[mt], fb_l[nt], acc[mt][nt], 0, 0, 0);
                acc[mt][nt] = __builtin_amdgcn_mfma_f32_16x16x32_bf16(fa_h[mt], fb_h[nt], acc[mt][nt], 0, 0, 0);
            }
    }

    #pragma unroll
    for (int nt = 0; nt < 4; ++nt) {
        const int n = n0 + wn*64 + nt*16 + ln15;
        const float bv = bias[n];
        #pragma unroll
        for (int mt = 0; mt < 4; ++mt) {
            const int mbase = m0 + wm*64 + mt*16 + lq*4;
            #pragma unroll
            for (int r = 0; r < 4; ++r) {
                int m = mbase + r;
                if (m < M) {
                    float val = acc[mt][nt][r] + bv;
                    int bg = m / 341;
                    int sp = m - bg*341;
                    size_t vb_ = ((size_t)bg*512 + n)*PKS + (size_t)((sp >> 3)*16 + (sp & 7));
                    unsigned short hb16 = f2bf(val);
                    vT[vb_]     = hb16;
                    vT[vb_ + 8] = f2bf(val - bf2f(hb16));
                }
            }
        }
    }
}

// ---------------------------------------------------------------------------
// Kernel 3b: PERSISTENT LSTM scan, GROUP-LOCAL LLC barrier (round-6, verified:
// 393 us/layer).  22 groups of 8 j-blocks; c in regs; h via sc0/sc1 dbuf.
// ---------------------------------------------------------------------------
__global__ __launch_bounds__(256)
void lstm_scan_k(const float* __restrict__ G,              // [32*341][2048]
                 const unsigned short* __restrict__ Whi,   // [2][1024][256]
                 const unsigned short* __restrict__ Wlo,
                 float* __restrict__ hb,                   // [2][2*341*256] dbuf
                 unsigned short* __restrict__ x_out,       // packed rows of 512
                 unsigned* __restrict__ bar)               // [22*64], zeroed
{
    const int j0 = blockIdx.x * 32;
    const int m0 = blockIdx.y * 32;
    const int d  = blockIdx.z;
    const int tid = threadIdx.x;
    const int w = tid >> 6, lane = tid & 63;
    const int mhalf = w & 1, gpair = w >> 1;
    const int ln15 = lane & 15, lq = lane >> 4;
    const size_t hsz = (size_t)2*SP*HD;
    unsigned* gbar = bar + (size_t)(blockIdx.y*2 + blockIdx.z)*64;

    __shared__ float Csh[32][132];

    int am = m0 + mhalf*16 + ln15; if (am > SP-1) am = SP-1;
    const int akoff = lq * 8;

    const unsigned short* WhiD = Whi + (size_t)d*1024*256;
    const unsigned short* WloD = Wlo + (size_t)d*1024*256;
    int nrow[4];
    #pragma unroll
    for (int t = 0; t < 4; ++t)
        nrow[t] = (gpair*2 + (t>>1))*256 + j0 + (t&1)*16 + ln15;

    const int emloc = tid >> 3;
    const int ej4   = (tid & 7) * 4;
    const int em    = m0 + emloc;

    floatx4 creg = (floatx4){0.f, 0.f, 0.f, 0.f};

    for (int s = 0; s < B_; ++s) {
        const int t_in = d ? (B_ - 1 - s) : s;
        float* hbuf_in  = hb + (size_t)(s & 1)*hsz;
        float* hbuf_out = hb + (size_t)((s+1) & 1)*hsz;

        floatx4 acc[4];
        #pragma unroll
        for (int t = 0; t < 4; ++t) acc[t] = (floatx4){0.f, 0.f, 0.f, 0.f};

        if (s > 0) {
            const float* p = hbuf_in + (size_t)d*HS + (size_t)am*HD + akoff;
            floatx4 hr[16];
            load_h16_llc(p, hr);
            #pragma unroll
            for (int kk = 0; kk < 8; ++kk) {
                const int ko = kk*32 + akoff;
                float vv[8] = {hr[2*kk][0], hr[2*kk][1], hr[2*kk][2], hr[2*kk][3],
                               hr[2*kk+1][0], hr[2*kk+1][1], hr[2*kk+1][2], hr[2*kk+1][3]};
                short8 ahi, alo;
                #pragma unroll
                for (int e = 0; e < 8; ++e) {
                    unsigned short hb16 = f2bf(vv[e]);
                    ahi[e] = (short)hb16;
                    alo[e] = (short)f2bf(vv[e] - bf2f(hb16));
                }
                #pragma unroll
                for (int t = 0; t < 4; ++t) {
                    short8 bhi = *(const short8*)(WhiD + (size_t)nrow[t]*HD + ko);
                    short8 blo = *(const short8*)(WloD + (size_t)nrow[t]*HD + ko);
                    acc[t] = __builtin_amdgcn_mfma_f32_16x16x32_bf16(alo, bhi, acc[t], 0, 0, 0);
                    acc[t] = __builtin_amdgcn_mfma_f32_16x16x32_bf16(ahi, blo, acc[t], 0, 0, 0);
                    acc[t] = __builtin_amdgcn_mfma_f32_16x16x32_bf16(ahi, bhi, acc[t], 0, 0, 0);
                }
            }
        }

        #pragma unroll
        for (int t = 0; t < 4; ++t) {
            int col = gpair*64 + (t>>1)*32 + (t&1)*16 + ln15;
            int rb  = mhalf*16 + lq*4;
            #pragma unroll
            for (int r = 0; r < 4; ++r)
                Csh[rb + r][col] = acc[t][r];
        }
        __syncthreads();

        if (em < SP) {
            size_t gb = ((size_t)t_in*SP + em)*2048 + (size_t)d*1024 + j0 + ej4;
            float4 gi4 = *(const float4*)&G[gb];
            float4 gf4 = *(const float4*)&G[gb + 256];
            float4 gg4 = *(const float4*)&G[gb + 512];
            float4 go4 = *(const float4*)&G[gb + 768];
            float hv[4];
            #pragma unroll
            for (int e = 0; e < 4; ++e) {
                float gi = Csh[emloc][     ej4+e] + (&gi4.x)[e];
                float gf = Csh[emloc][32 + ej4+e] + (&gf4.x)[e];
                float gg = Csh[emloc][64 + ej4+e] + (&gg4.x)[e];
                float go = Csh[emloc][96 + ej4+e] + (&go4.x)[e];
                float cn = sigmoidf_(gf)*creg[e] + sigmoidf_(gi)*tanhf(gg);
                creg[e] = cn;
                hv[e] = sigmoidf_(go)*tanhf(cn);
            }
            size_t cbase = ((size_t)d*SP + em)*HD + j0 + ej4;
            floatx4 ho = (floatx4){hv[0], hv[1], hv[2], hv[3]};
            store_f4_llc(&hbuf_out[cbase], ho);
            const int colg = d*HD + j0 + ej4;
            size_t xb = ((size_t)t_in*SP + em)*1024 + (size_t)(colg >> 3)*16 + (colg & 7);
            ushortx4 xh, xl;
            #pragma unroll
            for (int e = 0; e < 4; ++e) {
                unsigned short hb16 = f2bf(hv[e]);
                xh[e] = hb16;
                xl[e] = f2bf(hv[e] - bf2f(hb16));
            }
            *(ushortx4*)&x_out[xb]     = xh;
            *(ushortx4*)&x_out[xb + 8] = xl;
        }

        if (s < B_ - 1) {
            asm volatile("s_waitcnt vmcnt(0)" ::: "memory");
            __syncthreads();
            if (tid == 0) {
                atomicAdd(gbar, 1u);
                const unsigned target = (unsigned)(s + 1) * 8u;
                while (load_u32_llc(gbar) < target)
                    __builtin_amdgcn_s_sleep(2);
            }
            __syncthreads();
        }
    }
}

// ---------------------------------------------------------------------------
// Kernel 4a: scores strip + fused softmax -> P packed bf16 hi/lo.
// Block = 32 q-rows x ALL 384 k-cols (cols >= 341 masked).  RPE analytic,
// row softmax in-register (shfl over 16-lane tx group).  Grid (11, GRP, NH_).
// ---------------------------------------------------------------------------
__global__ __launch_bounds__(256)
void scores_sm_k(const float* __restrict__ q, const float* __restrict__ k,
                 unsigned short* __restrict__ Ppk, int g)
{
    const int h = blockIdx.z, bl = blockIdx.y, bg = g*GRP + bl;
    const int q0 = blockIdx.x * 32;
    const int tid = threadIdx.x;
    const int tx = tid & 15, ty = tid >> 4;
    __shared__ float qs[32][68];
    __shared__ float ks[64][68];
    {
        int jr = tid >> 3, c8 = (tid & 7) * 8;
        int qq = q0 + jr; if (qq > SP-1) qq = SP-1;
        const float* qp = &q[((size_t)bg*SP + qq)*512 + h*64 + c8];
        *(float4*)&qs[jr][c8]     = *(const float4*)qp;
        *(float4*)&qs[jr][c8 + 4] = *(const float4*)(qp + 4);
    }
    float sv[2][24];
    for (int kc = 0; kc < 6; ++kc) {
        __syncthreads();
        {
            int jr = tid >> 2, c16 = (tid & 3) * 16;
            int kr = kc*64 + jr; if (kr > SP-1) kr = SP-1;
            const float* kp = &k[((size_t)bg*SP + kr)*512 + h*64 + c16];
            #pragma unroll
            for (int u = 0; u < 4; ++u)
                *(float4*)&ks[jr][c16 + u*4] = *(const float4*)(kp + u*4);
        }
        __syncthreads();
        float a_[2][4] = {{0.f,0.f,0.f,0.f},{0.f,0.f,0.f,0.f}};
        for (int d4 = 0; d4 < 64; d4 += 4) {
            float4 a0 = *(const float4*)&qs[ty][d4];
            float4 a1 = *(const float4*)&qs[ty + 16][d4];
            float4 b[4];
            #pragma unroll
            for (int j = 0; j < 4; ++j) b[j] = *(const float4*)&ks[tx + 16*j][d4];
            #pragma unroll
            for (int j = 0; j < 4; ++j) {
                a_[0][j] += a0.x*b[j].x + a0.y*b[j].y + a0.z*b[j].z + a0.w*b[j].w;
                a_[1][j] += a1.x*b[j].x + a1.y*b[j].y + a1.z*b[j].z + a1.w*b[j].w;
            }
        }
        #pragma unroll
        for (int i = 0; i < 2; ++i)
            #pragma unroll
            for (int j = 0; j < 4; ++j) sv[i][kc*4 + j] = a_[i][j];
    }
    #pragma unroll
    for (int i = 0; i < 2; ++i) {
        const int qq = q0 + ty + 16*i;
        int r0 = 6*qq - 1; if (r0 < 0) r0 = 0;
        int r1 = 6*qq + 7; if (r1 > SLEN-1) r1 = SLEN-1;
        float m = -1e30f;
        #pragma unroll
        for (int jj = 0; jj < 24; ++jj) {
            const int col = (jj >> 2)*64 + (jj & 3)*16 + tx;
            float s;
            if (col < SP) {
                int c0 = 6*col - 1; if (c0 < 0) c0 = 0;
                int c1 = 6*col + 7;
                int dd1 = c1 - r0; if (dd1 < 0) dd1 = -dd1;
                int dd2 = r1 - c0; if (dd2 < 0) dd2 = -dd2;
                int den = dd1 > dd2 ? dd1 : dd2;
                s = (sv[i][jj] * 0.125f) * 2047.0f / (float)den;
            } else s = -1e30f;
            sv[i][jj] = s;
            m = fmaxf(m, s);
        }
        #pragma unroll
        for (int o = 1; o < 16; o <<= 1) m = fmaxf(m, __shfl_xor(m, o, 64));
        float sum = 0.0f;
        #pragma unroll
        for (int jj = 0; jj < 24; ++jj) {
            float v = expf(sv[i][jj] - m);
            sv[i][jj] = v;
            sum += v;
        }
        #pragma unroll
        for (int o = 1; o < 16; o <<= 1) sum += __shfl_xor(sum, o, 64);
        const float inv = 1.0f / sum;
        if (qq < SP) {
            const size_t pb = ((size_t)(h*GRP + bl)*SP + qq) * PKS;
            #pragma unroll
            for (int jj = 0; jj < 24; ++jj) {
                const int col = (jj >> 2)*64 + (jj & 3)*16 + tx;
                float p = sv[i][jj] * inv;
                unsigned short hb16 = f2bf(p);
                size_t pp = pb + (size_t)((col >> 3)*16 + (col & 7));
                Ppk[pp]     = hb16;
                Ppk[pp + 8] = f2bf(p - bf2f(hb16));
            }
        }
    }
}

// ---------------------------------------------------------------------------
// Kernel 4b: O = relu(P @ V) via split-bf16 MFMA.  A = Ppk (rows q, K=384
// packed), B = vT (rows dim, K=384 packed).  Tile 64q x 64dim, 4 waves
// (wave w = 16 q-rows x all 4 dim-tiles), 12 K-steps.  Grid (6, GRP, NH_).
// ---------------------------------------------------------------------------
__global__ __launch_bounds__(256)
void pv_bf_k(const unsigned short* __restrict__ Ppk, const unsigned short* __restrict__ vT,
             unsigned short* __restrict__ catp, int g)
{
    const int h = blockIdx.z, bl = blockIdx.y, bg = g*GRP + bl;
    const int q0 = blockIdx.x * 64;
    const int tid = threadIdx.x;
    const int lane = tid & 63, w = tid >> 6;
    const int ln15 = lane & 15, lq = lane >> 4;
    const int l8 = lane >> 3, lj = lane & 7;
    __shared__ unsigned short As[64*64];
    __shared__ unsigned short Bs[64*64];
    floatx4 acc[4];
    #pragma unroll
    for (int nt = 0; nt < 4; ++nt) acc[nt] = (floatx4){0.f,0.f,0.f,0.f};
    const int spos = lj ^ (l8 & 7);
    const size_t prow = (size_t)(h*GRP + bl)*SP;
    const size_t vrow = (size_t)bg*512 + h*64;

    for (int step = 0; step < 12; ++step) {
        const int ku = step * 64;          // ushort offset of K-step
        short8 va[2], vb[2];
        #pragma unroll
        for (int c = 0; c < 2; ++c) {
            const int r = w*16 + c*8 + l8;
            int qa = q0 + r; if (qa > SP-1) qa = SP-1;
            va[c] = *(const short8*)(Ppk + (prow + qa)*PKS + ku + lj*8);
            vb[c] = *(const short8*)(vT + (vrow + r)*PKS + ku + lj*8);
        }
        __syncthreads();
        #pragma unroll
        for (int c = 0; c < 2; ++c) {
            const int r = w*16 + c*8 + l8;
            *(short8*)&As[r*64 + spos*8] = va[c];
            *(short8*)&Bs[r*64 + spos*8] = vb[c];
        }
        __syncthreads();
        const int lrA = w*16 + ln15;
        short8 fa_h = *(const short8*)&As[lrA*64 + (((lq*2  ) ^ (lrA&7))*8)];
        short8 fa_l = *(const short8*)&As[lrA*64 + (((lq*2+1) ^ (lrA&7))*8)];
        #pragma unroll
        for (int nt = 0; nt < 4; ++nt) {
            const int lrB = nt*16 + ln15;
            short8 fb_h = *(const short8*)&Bs[lrB*64 + (((lq*2  ) ^ (lrB&7))*8)];
            short8 fb_l = *(const short8*)&Bs[lrB*64 + (((lq*2+1) ^ (lrB&7))*8)];
            acc[nt] = __builtin_amdgcn_mfma_f32_16x16x32_bf16(fa_l, fb_h, acc[nt], 0, 0, 0);
            acc[nt] = __builtin_amdgcn_mfma_f32_16x16x32_bf16(fa_h, fb_l, acc[nt], 0, 0, 0);
            acc[nt] = __builtin_amdgcn_mfma_f32_16x16x32_bf16(fa_h, fb_h, acc[nt], 0, 0, 0);
        }
    }
    #pragma unroll
    for (int nt = 0; nt < 4; ++nt) {
        const int colg = h*64 + nt*16 + ln15;
        #pragma unroll
        for (int r = 0; r < 4; ++r) {
            const int em = q0 + w*16 + lq*4 + r;
            if (em < SP) {
                float val = fmaxf(acc[nt][r], 0.0f);
                size_t xb = ((size_t)bg*SP + em)*1024 + (size_t)((colg >> 3)*16 + (colg & 7));
                unsigned short hb16 = f2bf(val);
                catp[xb]     = hb16;
                catp[xb + 8] = f2bf(val - bf2f(hb16));
            }
        }
    }
}

// ---------------------------------------------------------------------------
extern "C" void kernel_launch(void* const* d_in, const int* in_sizes, int n_in,
                              void* d_out, int out_size, void* d_ws, size_t ws_size,
                              hipStream_t stream)
{
    (void)in_sizes; (void)n_in; (void)out_size; (void)ws_size;
    const float* in    = (const float*)d_in[0];
    const float* cw    = (const float*)d_in[1];
    const float* gamma = (const float*)d_in[2];
    const float* beta  = (const float*)d_in[3];
    const float* Wih0  = (const float*)d_in[4];
    const float* Whh0  = (const float*)d_in[5];
    const float* b0    = (const float*)d_in[6];
    const float* Wih1  = (const float*)d_in[7];
    const float* Whh1  = (const float*)d_in[8];
    const float* b1    = (const float*)d_in[9];
    const float* Qw    = (const float*)d_in[10];
    const float* Qb    = (const float*)d_in[11];
    const float* Kw    = (const float*)d_in[12];
    const float* Kb    = (const float*)d_in[13];
    const float* Vw    = (const float*)d_in[14];
    const float* Vb    = (const float*)d_in[15];
    const float* mhw   = (const float*)d_in[16];
    const float* mhb   = (const float*)d_in[17];
    float* out = (float*)d_out;

    // workspace arena (floats)
    float* x0 = (float*)d_ws;                                   //  2,793,472 f
    float* G  = x0 + (size_t)RTOT*NF;                           // 22,347,776 f
    float* x1 = G  + (size_t)RTOT*2048;                         //  5,586,944 f
    float* x2 = x1 + (size_t)RTOT*512;                          //  5,586,944 f
    float* hb = x2 + (size_t)RTOT*512;                          //    349,184 f
    float* cb = hb + (size_t)2*2*SP*HD;                         //    174,592 f (barriers)

    float* qbuf = G;                                            // fp32 q
    float* kbuf = G + (size_t)RTOT*512;                         // fp32 k
    unsigned short* vT  = (unsigned short*)(G + (size_t)2*RTOT*512);   // 12,582,912 ush
    unsigned short* Ppk = (unsigned short*)(G + (size_t)2*RTOT*512 + 6291456); // 8,380,416 ush
    unsigned* bar = (unsigned*)cb;

    // packed-buffer aliases
    unsigned short* x0p = (unsigned short*)x0;
    unsigned short* whh1_hi = (unsigned short*)x0;              // after gemm1
    unsigned short* whh1_lo = whh1_hi + (size_t)524288;         // ends f 524,288
    unsigned short* qw_p = (unsigned short*)(x0 + (size_t)524288);  // x0 region, after whh1
    unsigned short* kw_p = qw_p + (size_t)524288;
    unsigned short* vw_p = kw_p + (size_t)524288;
    unsigned short* mw_p = vw_p + (size_t)524288;               // ends f 1,572,864 < 2,793,472
    unsigned short* wih0_p  = (unsigned short*)x2;
    unsigned short* wih1_p  = wih0_p + (size_t)1048576;
    unsigned short* whh0_hi = wih1_p + (size_t)2097152;
    unsigned short* whh0_lo = whh0_hi + (size_t)524288;
    unsigned short* x1p  = (unsigned short*)x1;
    unsigned short* catp = (unsigned short*)x1;
    unsigned short* x2p = (unsigned short*)x2;

    #define PACKGRID(n) dim3(((n) + 255) / 256)

    // 1. conv+bn+relu+pool -> x0p (packed)
    conv_pool_k<<<dim3(22, B_), 256, 0, stream>>>(in, cw, gamma, beta, x0p);
    // 2. pack Wih0 (octet) into x2 region
    pack8_k<<<PACKGRID(65536), 256, 0, stream>>>(Wih0, wih0_p, 65536);
    // 3. layer-1 input gates: G = x0 @ Wih0^T + b0   (K=256)
    gemm_bf_k<0><<<dim3(16, 86), 256, 0, stream>>>(x0p, wih0_p, b0, G, RTOT, 2048, 256);
    // 4. pack Whh0 (x2 tail), Whh1 (x0, dead after gemm1), Wih1 (x2)
    pack4_k<<<PACKGRID(131072), 256, 0, stream>>>(Whh0, whh0_hi, whh0_lo, 131072);
    pack4_k<<<PACKGRID(131072), 256, 0, stream>>>(Whh1, whh1_hi, whh1_lo, 131072);
    pack8_k<<<PACKGRID(131072), 256, 0, stream>>>(Wih1, wih1_p, 131072);
    // 5. layer-1 scan -> x1p (round-6 persistent, group-local LLC barriers)
    hipMemsetAsync(bar, 0, 22*64*sizeof(unsigned), stream);
    {
        const float* a0 = G; const unsigned short* a1 = whh0_hi; const unsigned short* a2 = whh0_lo;
        float* a3 = hb; unsigned short* a4 = x1p; unsigned* a5 = bar;
        void* kargs[] = {&a0, &a1, &a2, &a3, &a4, &a5};
        hipLaunchCooperativeKernel((void*)lstm_scan_k, dim3(8, 11, 2), dim3(256, 1, 1), kargs, 0, stream);
    }
    // 6. layer-2 input gates: G = x1 @ Wih1^T + b1   (K=512)
    gemm_bf_k<0><<<dim3(16, 86), 256, 0, stream>>>(x1p, wih1_p, b1, G, RTOT, 2048, 512);
    // 7. layer-2 scan -> x2p
    hipMemsetAsync(bar, 0, 22*64*sizeof(unsigned), stream);
    {
        const float* a0 = G; const unsigned short* a1 = whh1_hi; const unsigned short* a2 = whh1_lo;
        float* a3 = hb; unsigned short* a4 = x2p; unsigned* a5 = bar;
        void* kargs[] = {&a0, &a1, &a2, &a3, &a4, &a5};
        hipLaunchCooperativeKernel((void*)lstm_scan_k, dim3(8, 11, 2), dim3(256, 1, 1), kargs, 0, stream);
    }
    // 8. pack QKV/mh weights into x0 region (whh1 dead after scan2)
    pack8_k<<<PACKGRID(32768), 256, 0, stream>>>(Qw,  qw_p, 32768);
    pack8_k<<<PACKGRID(32768), 256, 0, stream>>>(Kw,  kw_p, 32768);
    pack8_k<<<PACKGRID(32768), 256, 0, stream>>>(Vw,  vw_p, 32768);
    pack8_k<<<PACKGRID(32768), 256, 0, stream>>>(mhw, mw_p, 32768);
    // 9. Q/K projections (fp32), V projection transposed+packed (zero pad first)
    gemm_bf_k<0><<<dim3(4, 86), 256, 0, stream>>>(x2p, qw_p, Qb, qbuf, RTOT, 512, 512);
    gemm_bf_k<0><<<dim3(4, 86), 256, 0, stream>>>(x2p, kw_p, Kb, kbuf, RTOT, 512, 512);
    hipMemsetAsync(vT, 0, (size_t)B_*512*PKS*sizeof(unsigned short), stream);
    gemm_vT_k<<<dim3(4, 86), 256, 0, stream>>>(x2p, vw_p, Vb, vT, RTOT, 512, 512);
    // 10. attention: fused scores+softmax -> packed P, then MFMA PV -> catp
    for (int g = 0; g < B_/GRP; ++g) {
        scores_sm_k<<<dim3(11, GRP, NH_), 256, 0, stream>>>(qbuf, kbuf, Ppk, g);
        pv_bf_k    <<<dim3(6,  GRP, NH_), 256, 0, stream>>>(Ppk, vT, catp, g);
    }
    // 11. final linear + relu
    gemm_bf_k<1><<<dim3(4, 86), 256, 0, stream>>>(catp, mw_p, mhb, out, RTOT, 512, 512);
    #undef PACKGRID
}

// Round 10
// 1696.940 us; speedup vs baseline: 2.2243x; 1.0011x over previous
//
#include <hip/hip_runtime.h>
#include <math.h>

// Problem constants
#define B_    32
#define CIN   4
#define SLEN  2048
#define NF    256
#define HD    256          // LSTM hidden per direction
#define SP    341          // post conv+pool sequence length
#define RTOT  (B_*SP)      // 10912 rows
#define NH_   8
#define DH_   64
#define GRP   4            // batches per attention group
#define HS    (SP*HD)      // 87296: per-dir h elems
#define PKS   768          // packed P row stride in ushorts (384 elems)
#define BSTR  136          // pv LDS row stride (ushorts, 16B-aligned rows)

typedef __attribute__((ext_vector_type(8))) short short8;
typedef __attribute__((ext_vector_type(4))) float floatx4;
typedef __attribute__((ext_vector_type(4))) unsigned short ushortx4;
typedef __attribute__((ext_vector_type(8))) unsigned short ushort8;

__device__ __forceinline__ float sigmoidf_(float x) { return 1.0f / (1.0f + expf(-x)); }

__device__ __forceinline__ unsigned short f2bf(float x) {
    unsigned int u = __float_as_uint(x);
    unsigned int r = (u + 0x7FFF + ((u >> 16) & 1)) >> 16;   // RNE
    return (unsigned short)r;
}
__device__ __forceinline__ float bf2f(unsigned short b) {
    return __uint_as_float(((unsigned int)b) << 16);
}

// ---- LLC-coherent (Infinity Cache) access helpers: sc0 sc1 bypass L1/L2 ----
__device__ __forceinline__ void store_f4_llc(float* p, floatx4 v)
{
    asm volatile("global_store_dwordx4 %0, %1, off sc0 sc1" :: "v"(p), "v"(v) : "memory");
}
__device__ __forceinline__ unsigned load_u32_llc(const unsigned* p)
{
    unsigned r;
    asm volatile("global_load_dword %0, %1, off sc0 sc1\n\ts_waitcnt vmcnt(0)"
                 : "=v"(r) : "v"(p) : "memory");
    return r;
}
// 16 x dwordx4 from one base; single trailing waitcnt INSIDE the asm.
__device__ __forceinline__ void load_h16_llc(const float* p, floatx4* r)
{
    asm volatile(
        "global_load_dwordx4 %0, %16, off sc0 sc1\n\t"
        "global_load_dwordx4 %1, %16, off offset:16 sc0 sc1\n\t"
        "global_load_dwordx4 %2, %16, off offset:128 sc0 sc1\n\t"
        "global_load_dwordx4 %3, %16, off offset:144 sc0 sc1\n\t"
        "global_load_dwordx4 %4, %16, off offset:256 sc0 sc1\n\t"
        "global_load_dwordx4 %5, %16, off offset:272 sc0 sc1\n\t"
        "global_load_dwordx4 %6, %16, off offset:384 sc0 sc1\n\t"
        "global_load_dwordx4 %7, %16, off offset:400 sc0 sc1\n\t"
        "global_load_dwordx4 %8, %16, off offset:512 sc0 sc1\n\t"
        "global_load_dwordx4 %9, %16, off offset:528 sc0 sc1\n\t"
        "global_load_dwordx4 %10, %16, off offset:640 sc0 sc1\n\t"
        "global_load_dwordx4 %11, %16, off offset:656 sc0 sc1\n\t"
        "global_load_dwordx4 %12, %16, off offset:768 sc0 sc1\n\t"
        "global_load_dwordx4 %13, %16, off offset:784 sc0 sc1\n\t"
        "global_load_dwordx4 %14, %16, off offset:896 sc0 sc1\n\t"
        "global_load_dwordx4 %15, %16, off offset:912 sc0 sc1\n\t"
        "s_waitcnt vmcnt(0)"
        : "=&v"(r[0]), "=&v"(r[1]), "=&v"(r[2]), "=&v"(r[3]),
          "=&v"(r[4]), "=&v"(r[5]), "=&v"(r[6]), "=&v"(r[7]),
          "=&v"(r[8]), "=&v"(r[9]), "=&v"(r[10]), "=&v"(r[11]),
          "=&v"(r[12]), "=&v"(r[13]), "=&v"(r[14]), "=&v"(r[15])
        : "v"(p)
        : "memory");
}

// ---------------------------------------------------------------------------
// Packed bf16 hi/lo "octet" layout: row of K fp32 -> 2K ushorts; octet o:
// [16o..16o+7]=hi, [16o+8..16o+15]=lo.  K-step 32 = 128 contiguous bytes.
// ---------------------------------------------------------------------------

// Kernel 1: Conv1d(4->256,k13,pad6)+BN+ReLU+MaxPool1d(6) -> x0 packed
__global__ __launch_bounds__(256)
void conv_pool_k(const float* __restrict__ in, const float* __restrict__ cw,
                 const float* __restrict__ gamma, const float* __restrict__ beta,
                 unsigned short* __restrict__ x0p)
{
    const int b  = blockIdx.y;
    const int s0 = blockIdx.x * 16;
    const int co = threadIdx.x;
    __shared__ float ins[CIN][16*6 + 12];
    for (int idx = threadIdx.x; idx < CIN*108; idx += 256) {
        int ci = idx / 108, o = idx % 108;
        int pos = 6*s0 - 6 + o;
        ins[ci][o] = (pos >= 0 && pos < SLEN) ? in[(b*CIN + ci)*SLEN + pos] : 0.0f;
    }
    float wreg[52];
    {
        const float4* wp = (const float4*)(cw + co*52);
        #pragma unroll
        for (int j4 = 0; j4 < 13; ++j4) {
            float4 w4 = wp[j4];
            wreg[j4*4+0]=w4.x; wreg[j4*4+1]=w4.y; wreg[j4*4+2]=w4.z; wreg[j4*4+3]=w4.w;
        }
    }
    const float scale = gamma[co] * (1.0f / sqrtf(1.0f + 1e-5f));
    const float shift = beta[co];
    __syncthreads();
    for (int si = 0; si < 16; ++si) {
        int s = s0 + si;
        if (s >= SP) break;
        float win[CIN][18];
        #pragma unroll
        for (int ci = 0; ci < CIN; ++ci)
            #pragma unroll
            for (int o = 0; o < 18; ++o)
                win[ci][o] = ins[ci][6*si + o];
        float m = -1e30f;
        #pragma unroll
        for (int p6 = 0; p6 < 6; ++p6) {
            float acc = 0.0f;
            #pragma unroll
            for (int ci = 0; ci < CIN; ++ci)
                #pragma unroll
                for (int kk = 0; kk < 13; ++kk)
                    acc += win[ci][p6+kk] * wreg[ci*13+kk];
            float val = acc * scale + shift;
            val = fmaxf(val, 0.0f);
            m = fmaxf(m, val);
        }
        unsigned short hb_ = f2bf(m);
        unsigned short lb_ = f2bf(m - bf2f(hb_));
        size_t rb = (size_t)(b*SP + s)*512 + (size_t)(co >> 3)*16 + (co & 7);
        x0p[rb]     = hb_;
        x0p[rb + 8] = lb_;
    }
}

// Kernel 2a: fp32 -> separate hi/lo pack (for lstm Whh)
__global__ __launch_bounds__(256)
void pack4_k(const float* __restrict__ W, unsigned short* __restrict__ hi,
             unsigned short* __restrict__ lo, int n4)
{
    int i = blockIdx.x * 256 + threadIdx.x;
    if (i >= n4) return;
    float4 x = *((const float4*)W + i);
    float v[4] = {x.x, x.y, x.z, x.w};
    ushortx4 h, l;
    #pragma unroll
    for (int e = 0; e < 4; ++e) {
        unsigned short hb = f2bf(v[e]);
        h[e] = hb;
        l[e] = f2bf(v[e] - bf2f(hb));
    }
    *((ushortx4*)hi + i) = h;
    *((ushortx4*)lo + i) = l;
}

// Kernel 2b: fp32 -> interleaved octet pack (8 elems/thread)
__global__ __launch_bounds__(256)
void pack8_k(const float* __restrict__ W, unsigned short* __restrict__ O, int n8)
{
    int i = blockIdx.x * 256 + threadIdx.x;
    if (i >= n8) return;
    const float4* wp = (const float4*)W + (size_t)i*2;
    float4 a = wp[0], b = wp[1];
    float v[8] = {a.x,a.y,a.z,a.w,b.x,b.y,b.z,b.w};
    ushort8 h, l;
    #pragma unroll
    for (int e = 0; e < 8; ++e) {
        unsigned short hb = f2bf(v[e]);
        h[e] = hb;
        l[e] = f2bf(v[e] - bf2f(hb));
    }
    *(ushort8*)(O + (size_t)i*16)     = h;
    *(ushort8*)(O + (size_t)i*16 + 8) = l;
}

// ---------------------------------------------------------------------------
// Kernel 3: split-bf16 MFMA GEMM, packed octet operands (unchanged).
// ---------------------------------------------------------------------------
template<int RELU>
__global__ __launch_bounds__(256)
void gemm_bf_k(const unsigned short* __restrict__ Ap, const unsigned short* __restrict__ Bp,
               const float* __restrict__ bias, float* __restrict__ C,
               int M, int N, int K)
{
    const int n0 = blockIdx.x * 128;
    const int m0 = blockIdx.y * 128;
    const int tid = threadIdx.x;
    const int lane = tid & 63;
    const int w = tid >> 6;
    const int wm = w >> 1, wn = w & 1;
    const int ln15 = lane & 15, lq = lane >> 4;
    const int l8 = lane >> 3, lj = lane & 7;
    const size_t rstr = 2*(size_t)K;

    __shared__ unsigned short As[128*64];
    __shared__ unsigned short Bs[128*64];

    floatx4 acc[4][4];
    #pragma unroll
    for (int i = 0; i < 4; ++i)
        #pragma unroll
        for (int j = 0; j < 4; ++j) acc[i][j] = (floatx4){0.f, 0.f, 0.f, 0.f};

    int rloc[4];
    #pragma unroll
    for (int c = 0; c < 4; ++c) rloc[c] = w*32 + c*8 + l8;
    const int spos = lj ^ (l8 & 7);

    for (int k0 = 0; k0 < K; k0 += 32) {
        short8 va[4], vb[4];
        #pragma unroll
        for (int c = 0; c < 4; ++c) {
            int gra = m0 + rloc[c]; if (gra >= M) gra = M - 1;
            va[c] = *(const short8*)(Ap + (size_t)gra*rstr + k0*2 + lj*8);
            vb[c] = *(const short8*)(Bp + (size_t)(n0 + rloc[c])*rstr + k0*2 + lj*8);
        }
        __syncthreads();
        #pragma unroll
        for (int c = 0; c < 4; ++c) {
            *(short8*)&As[rloc[c]*64 + spos*8] = va[c];
            *(short8*)&Bs[rloc[c]*64 + spos*8] = vb[c];
        }
        __syncthreads();

        short8 fa_h[4], fa_l[4], fb_h[4], fb_l[4];
        #pragma unroll
        for (int mt = 0; mt < 4; ++mt) {
            const int lr = wm*64 + mt*16 + ln15;
            fa_h[mt] = *(const short8*)&As[lr*64 + (((lq*2  ) ^ (lr&7))*8)];
            fa_l[mt] = *(const short8*)&As[lr*64 + (((lq*2+1) ^ (lr&7))*8)];
        }
        #pragma unroll
        for (int nt = 0; nt < 4; ++nt) {
            const int lr = wn*64 + nt*16 + ln15;
            fb_h[nt] = *(const short8*)&Bs[lr*64 + (((lq*2  ) ^ (lr&7))*8)];
            fb_l[nt] = *(const short8*)&Bs[lr*64 + (((lq*2+1) ^ (lr&7))*8)];
        }
        #pragma unroll
        for (int mt = 0; mt < 4; ++mt)
            #pragma unroll
            for (int nt = 0; nt < 4; ++nt) {
                acc[mt][nt] = __builtin_amdgcn_mfma_f32_16x16x32_bf16(fa_l[mt], fb_h[nt], acc[mt][nt], 0, 0, 0);
                acc[mt][nt] = __builtin_amdgcn_mfma_f32_16x16x32_bf16(fa_h[mt], fb_l[nt], acc[mt][nt], 0, 0, 0);
                acc[mt][nt] = __builtin_amdgcn_mfma_f32_16x16x32_bf16(fa_h[mt], fb_h[nt], acc[mt][nt], 0, 0, 0);
            }
    }

    #pragma unroll
    for (int nt = 0; nt < 4; ++nt) {
        const int n = n0 + wn*64 + nt*16 + ln15;
        const float bv = bias[n];
        #pragma unroll
        for (int mt = 0; mt < 4; ++mt) {
            const int mbase = m0 + wm*64 + mt*16 + lq*4;
            #pragma unroll
            for (int r = 0; r < 4; ++r) {
                int m = mbase + r;
                if (m < M) {
                    float val = acc[mt][nt][r] + bv;
                    if (RELU) val = fmaxf(val, 0.0f);
                    C[(size_t)m*N + n] = val;
                }
            }
        }
    }
}

// ---------------------------------------------------------------------------
// Kernel 3b: PERSISTENT LSTM scan, GROUP-LOCAL LLC barrier (round-6, verified:
// 393 us/layer).  22 groups of 8 j-blocks; c in regs; h via sc0/sc1 dbuf.
// ---------------------------------------------------------------------------
__global__ __launch_bounds__(256)
void lstm_scan_k(const float* __restrict__ G,              // [32*341][2048]
                 const unsigned short* __restrict__ Whi,   // [2][1024][256]
                 const unsigned short* __restrict__ Wlo,
                 float* __restrict__ hb,                   // [2][2*341*256] dbuf
                 unsigned short* __restrict__ x_out,       // packed rows of 512
                 unsigned* __restrict__ bar)               // [22*64], zeroed
{
    const int j0 = blockIdx.x * 32;
    const int m0 = blockIdx.y * 32;
    const int d  = blockIdx.z;
    const int tid = threadIdx.x;
    const int w = tid >> 6, lane = tid & 63;
    const int mhalf = w & 1, gpair = w >> 1;
    const int ln15 = lane & 15, lq = lane >> 4;
    const size_t hsz = (size_t)2*SP*HD;
    unsigned* gbar = bar + (size_t)(blockIdx.y*2 + blockIdx.z)*64;

    __shared__ float Csh[32][132];

    int am = m0 + mhalf*16 + ln15; if (am > SP-1) am = SP-1;
    const int akoff = lq * 8;

    const unsigned short* WhiD = Whi + (size_t)d*1024*256;
    const unsigned short* WloD = Wlo + (size_t)d*1024*256;
    int nrow[4];
    #pragma unroll
    for (int t = 0; t < 4; ++t)
        nrow[t] = (gpair*2 + (t>>1))*256 + j0 + (t&1)*16 + ln15;

    const int emloc = tid >> 3;
    const int ej4   = (tid & 7) * 4;
    const int em    = m0 + emloc;

    floatx4 creg = (floatx4){0.f, 0.f, 0.f, 0.f};

    for (int s = 0; s < B_; ++s) {
        const int t_in = d ? (B_ - 1 - s) : s;
        float* hbuf_in  = hb + (size_t)(s & 1)*hsz;
        float* hbuf_out = hb + (size_t)((s+1) & 1)*hsz;

        floatx4 acc[4];
        #pragma unroll
        for (int t = 0; t < 4; ++t) acc[t] = (floatx4){0.f, 0.f, 0.f, 0.f};

        if (s > 0) {
            const float* p = hbuf_in + (size_t)d*HS + (size_t)am*HD + akoff;
            floatx4 hr[16];
            load_h16_llc(p, hr);
            #pragma unroll
            for (int kk = 0; kk < 8; ++kk) {
                const int ko = kk*32 + akoff;
                float vv[8] = {hr[2*kk][0], hr[2*kk][1], hr[2*kk][2], hr[2*kk][3],
                               hr[2*kk+1][0], hr[2*kk+1][1], hr[2*kk+1][2], hr[2*kk+1][3]};
                short8 ahi, alo;
                #pragma unroll
                for (int e = 0; e < 8; ++e) {
                    unsigned short hb16 = f2bf(vv[e]);
                    ahi[e] = (short)hb16;
                    alo[e] = (short)f2bf(vv[e] - bf2f(hb16));
                }
                #pragma unroll
                for (int t = 0; t < 4; ++t) {
                    short8 bhi = *(const short8*)(WhiD + (size_t)nrow[t]*HD + ko);
                    short8 blo = *(const short8*)(WloD + (size_t)nrow[t]*HD + ko);
                    acc[t] = __builtin_amdgcn_mfma_f32_16x16x32_bf16(alo, bhi, acc[t], 0, 0, 0);
                    acc[t] = __builtin_amdgcn_mfma_f32_16x16x32_bf16(ahi, blo, acc[t], 0, 0, 0);
                    acc[t] = __builtin_amdgcn_mfma_f32_16x16x32_bf16(ahi, bhi, acc[t], 0, 0, 0);
                }
            }
        }

        #pragma unroll
        for (int t = 0; t < 4; ++t) {
            int col = gpair*64 + (t>>1)*32 + (t&1)*16 + ln15;
            int rb  = mhalf*16 + lq*4;
            #pragma unroll
            for (int r = 0; r < 4; ++r)
                Csh[rb + r][col] = acc[t][r];
        }
        __syncthreads();

        if (em < SP) {
            size_t gb = ((size_t)t_in*SP + em)*2048 + (size_t)d*1024 + j0 + ej4;
            float4 gi4 = *(const float4*)&G[gb];
            float4 gf4 = *(const float4*)&G[gb + 256];
            float4 gg4 = *(const float4*)&G[gb + 512];
            float4 go4 = *(const float4*)&G[gb + 768];
            float hv[4];
            #pragma unroll
            for (int e = 0; e < 4; ++e) {
                float gi = Csh[emloc][     ej4+e] + (&gi4.x)[e];
                float gf = Csh[emloc][32 + ej4+e] + (&gf4.x)[e];
                float gg = Csh[emloc][64 + ej4+e] + (&gg4.x)[e];
                float go = Csh[emloc][96 + ej4+e] + (&go4.x)[e];
                float cn = sigmoidf_(gf)*creg[e] + sigmoidf_(gi)*tanhf(gg);
                creg[e] = cn;
                hv[e] = sigmoidf_(go)*tanhf(cn);
            }
            size_t cbase = ((size_t)d*SP + em)*HD + j0 + ej4;
            floatx4 ho = (floatx4){hv[0], hv[1], hv[2], hv[3]};
            store_f4_llc(&hbuf_out[cbase], ho);
            const int colg = d*HD + j0 + ej4;
            size_t xb = ((size_t)t_in*SP + em)*1024 + (size_t)(colg >> 3)*16 + (colg & 7);
            ushortx4 xh, xl;
            #pragma unroll
            for (int e = 0; e < 4; ++e) {
                unsigned short hb16 = f2bf(hv[e]);
                xh[e] = hb16;
                xl[e] = f2bf(hv[e] - bf2f(hb16));
            }
            *(ushortx4*)&x_out[xb]     = xh;
            *(ushortx4*)&x_out[xb + 8] = xl;
        }

        if (s < B_ - 1) {
            asm volatile("s_waitcnt vmcnt(0)" ::: "memory");
            __syncthreads();
            if (tid == 0) {
                atomicAdd(gbar, 1u);
                const unsigned target = (unsigned)(s + 1) * 8u;
                while (load_u32_llc(gbar) < target)
                    __builtin_amdgcn_s_sleep(2);
            }
            __syncthreads();
        }
    }
}

// ---------------------------------------------------------------------------
// Kernel 4a: scores strip + fused softmax -> P packed bf16 hi/lo.
// Block = 32 q-rows x ALL 384 k-cols (cols >= 341 masked -> P exactly 0).
// RPE analytic, row softmax in-register (shfl over 16-lane tx group).
// Grid (11, GRP, NH_).  (unchanged from round 9 — passed)
// ---------------------------------------------------------------------------
__global__ __launch_bounds__(256)
void scores_sm_k(const float* __restrict__ q, const float* __restrict__ k,
                 unsigned short* __restrict__ Ppk, int g)
{
    const int h = blockIdx.z, bl = blockIdx.y, bg = g*GRP + bl;
    const int q0 = blockIdx.x * 32;
    const int tid = threadIdx.x;
    const int tx = tid & 15, ty = tid >> 4;
    __shared__ float qs[32][68];
    __shared__ float ks[64][68];
    {
        int jr = tid >> 3, c8 = (tid & 7) * 8;
        int qq = q0 + jr; if (qq > SP-1) qq = SP-1;
        const float* qp = &q[((size_t)bg*SP + qq)*512 + h*64 + c8];
        *(float4*)&qs[jr][c8]     = *(const float4*)qp;
        *(float4*)&qs[jr][c8 + 4] = *(const float4*)(qp + 4);
    }
    float sv[2][24];
    for (int kc = 0; kc < 6; ++kc) {
        __syncthreads();
        {
            int jr = tid >> 2, c16 = (tid & 3) * 16;
            int kr = kc*64 + jr; if (kr > SP-1) kr = SP-1;
            const float* kp = &k[((size_t)bg*SP + kr)*512 + h*64 + c16];
            #pragma unroll
            for (int u = 0; u < 4; ++u)
                *(float4*)&ks[jr][c16 + u*4] = *(const float4*)(kp + u*4);
        }
        __syncthreads();
        float a_[2][4] = {{0.f,0.f,0.f,0.f},{0.f,0.f,0.f,0.f}};
        for (int d4 = 0; d4 < 64; d4 += 4) {
            float4 a0 = *(const float4*)&qs[ty][d4];
            float4 a1 = *(const float4*)&qs[ty + 16][d4];
            float4 b[4];
            #pragma unroll
            for (int j = 0; j < 4; ++j) b[j] = *(const float4*)&ks[tx + 16*j][d4];
            #pragma unroll
            for (int j = 0; j < 4; ++j) {
                a_[0][j] += a0.x*b[j].x + a0.y*b[j].y + a0.z*b[j].z + a0.w*b[j].w;
                a_[1][j] += a1.x*b[j].x + a1.y*b[j].y + a1.z*b[j].z + a1.w*b[j].w;
            }
        }
        #pragma unroll
        for (int i = 0; i < 2; ++i)
            #pragma unroll
            for (int j = 0; j < 4; ++j) sv[i][kc*4 + j] = a_[i][j];
    }
    #pragma unroll
    for (int i = 0; i < 2; ++i) {
        const int qq = q0 + ty + 16*i;
        int r0 = 6*qq - 1; if (r0 < 0) r0 = 0;
        int r1 = 6*qq + 7; if (r1 > SLEN-1) r1 = SLEN-1;
        float m = -1e30f;
        #pragma unroll
        for (int jj = 0; jj < 24; ++jj) {
            const int col = (jj >> 2)*64 + (jj & 3)*16 + tx;
            float s;
            if (col < SP) {
                int c0 = 6*col - 1; if (c0 < 0) c0 = 0;
                int c1 = 6*col + 7;
                int dd1 = c1 - r0; if (dd1 < 0) dd1 = -dd1;
                int dd2 = r1 - c0; if (dd2 < 0) dd2 = -dd2;
                int den = dd1 > dd2 ? dd1 : dd2;
                s = (sv[i][jj] * 0.125f) * 2047.0f / (float)den;
            } else s = -1e30f;
            sv[i][jj] = s;
            m = fmaxf(m, s);
        }
        #pragma unroll
        for (int o = 1; o < 16; o <<= 1) m = fmaxf(m, __shfl_xor(m, o, 64));
        float sum = 0.0f;
        #pragma unroll
        for (int jj = 0; jj < 24; ++jj) {
            float v = expf(sv[i][jj] - m);
            sv[i][jj] = v;
            sum += v;
        }
        #pragma unroll
        for (int o = 1; o < 16; o <<= 1) sum += __shfl_xor(sum, o, 64);
        const float inv = 1.0f / sum;
        if (qq < SP) {
            const size_t pb = ((size_t)(h*GRP + bl)*SP + qq) * PKS;
            #pragma unroll
            for (int jj = 0; jj < 24; ++jj) {
                const int col = (jj >> 2)*64 + (jj & 3)*16 + tx;
                float p = sv[i][jj] * inv;
                unsigned short hb16 = f2bf(p);
                size_t pp = pb + (size_t)((col >> 3)*16 + (col & 7));
                Ppk[pp]     = hb16;
                Ppk[pp + 8] = f2bf(p - bf2f(hb16));
            }
        }
    }
}

// ---------------------------------------------------------------------------
// Kernel 4b v2: O = relu(P @ V) via split-bf16 MFMA.  A = Ppk (packed rows),
// B built IN LDS from fp32 vbuf: coalesced float4 loads, in-register hi/lo
// split, transposed 2B LDS writes -> Bs[dim][kv-octets].  Tile 64q x 64dim,
// 4 waves, 6 chunks x 2 K-steps.  Grid (6, GRP, NH_).
// ---------------------------------------------------------------------------
__global__ __launch_bounds__(256)
void pv_bf_k(const unsigned short* __restrict__ Ppk, const float* __restrict__ vbuf,
             unsigned short* __restrict__ catp, int g)
{
    const int h = blockIdx.z, bl = blockIdx.y, bg = g*GRP + bl;
    const int q0 = blockIdx.x * 64;
    const int tid = threadIdx.x;
    const int lane = tid & 63, w = tid >> 6;
    const int ln15 = lane & 15, lq = lane >> 4;
    __shared__ unsigned short As[64][BSTR];
    __shared__ unsigned short Bs[64][BSTR];
    floatx4 acc[4];
    #pragma unroll
    for (int nt = 0; nt < 4; ++nt) acc[nt] = (floatx4){0.f,0.f,0.f,0.f};
    const size_t prow = (size_t)(h*GRP + bl)*SP;
    const int sr = tid >> 2;            // 0..63: q-row (A) / kv-row (B)
    const int sa = (tid & 3) * 32;      // A: 32-ushort segment
    const int sd = (tid & 3) * 16;      // B: 16-dim segment

    for (int chunk = 0; chunk < 6; ++chunk) {
        // A: packed-P window [chunk*128, +128) for q-row sr (coalesced 16B)
        int qa = q0 + sr; if (qa > SP-1) qa = SP-1;
        const unsigned short* ap = Ppk + (prow + qa)*PKS + chunk*128 + sa;
        short8 a0 = *(const short8*)ap;
        short8 a1 = *(const short8*)(ap + 8);
        short8 a2 = *(const short8*)(ap + 16);
        short8 a3 = *(const short8*)(ap + 24);
        // B: fp32 V row kv = chunk*64+sr, dims sd..sd+15 (coalesced float4)
        const int kr = chunk*64 + sr;
        float vv[16];
        if (kr < SP) {
            const float* vp = &vbuf[((size_t)bg*SP + kr)*512 + h*64 + sd];
            *(float4*)&vv[0]  = ((const float4*)vp)[0];
            *(float4*)&vv[4]  = ((const float4*)vp)[1];
            *(float4*)&vv[8]  = ((const float4*)vp)[2];
            *(float4*)&vv[12] = ((const float4*)vp)[3];
        } else {
            #pragma unroll
            for (int e = 0; e < 16; ++e) vv[e] = 0.0f;
        }
        __syncthreads();   // previous chunk's fragment reads complete
        *(short8*)&As[sr][sa]      = a0;
        *(short8*)&As[sr][sa + 8]  = a1;
        *(short8*)&As[sr][sa + 16] = a2;
        *(short8*)&As[sr][sa + 24] = a3;
        {
            const int c = (sr >> 3)*16 + (sr & 7);   // kv octet position
            #pragma unroll
            for (int e = 0; e < 16; ++e) {
                unsigned short hb16 = f2bf(vv[e]);
                Bs[sd + e][c]     = hb16;
                Bs[sd + e][c + 8] = f2bf(vv[e] - bf2f(hb16));
            }
        }
        __syncthreads();
        #pragma unroll
        for (int s = 0; s < 2; ++s) {
            const int ko = s*64 + lq*16;
            short8 fa_h = *(const short8*)&As[w*16 + ln15][ko];
            short8 fa_l = *(const short8*)&As[w*16 + ln15][ko + 8];
            #pragma unroll
            for (int nt = 0; nt < 4; ++nt) {
                short8 fb_h = *(const short8*)&Bs[nt*16 + ln15][ko];
                short8 fb_l = *(const short8*)&Bs[nt*16 + ln15][ko + 8];
                acc[nt] = __builtin_amdgcn_mfma_f32_16x16x32_bf16(fa_l, fb_h, acc[nt], 0, 0, 0);
                acc[nt] = __builtin_amdgcn_mfma_f32_16x16x32_bf16(fa_h, fb_l, acc[nt], 0, 0, 0);
                acc[nt] = __builtin_amdgcn_mfma_f32_16x16x32_bf16(fa_h, fb_h, acc[nt], 0, 0, 0);
            }
        }
    }
    // epilogue (same mapping as round 9 — verified): n=lane&15, m=lq*4+r
    #pragma unroll
    for (int nt = 0; nt < 4; ++nt) {
        const int colg = h*64 + nt*16 + ln15;
        #pragma unroll
        for (int r = 0; r < 4; ++r) {
            const int em = q0 + w*16 + lq*4 + r;
            if (em < SP) {
                float val = fmaxf(acc[nt][r], 0.0f);
                size_t xb = ((size_t)bg*SP + em)*1024 + (size_t)((colg >> 3)*16 + (colg & 7));
                unsigned short hb16 = f2bf(val);
                catp[xb]     = hb16;
                catp[xb + 8] = f2bf(val - bf2f(hb16));
            }
        }
    }
}

// ---------------------------------------------------------------------------
extern "C" void kernel_launch(void* const* d_in, const int* in_sizes, int n_in,
                              void* d_out, int out_size, void* d_ws, size_t ws_size,
                              hipStream_t stream)
{
    (void)in_sizes; (void)n_in; (void)out_size; (void)ws_size;
    const float* in    = (const float*)d_in[0];
    const float* cw    = (const float*)d_in[1];
    const float* gamma = (const float*)d_in[2];
    const float* beta  = (const float*)d_in[3];
    const float* Wih0  = (const float*)d_in[4];
    const float* Whh0  = (const float*)d_in[5];
    const float* b0    = (const float*)d_in[6];
    const float* Wih1  = (const float*)d_in[7];
    const float* Whh1  = (const float*)d_in[8];
    const float* b1    = (const float*)d_in[9];
    const float* Qw    = (const float*)d_in[10];
    const float* Qb    = (const float*)d_in[11];
    const float* Kw    = (const float*)d_in[12];
    const float* Kb    = (const float*)d_in[13];
    const float* Vw    = (const float*)d_in[14];
    const float* Vb    = (const float*)d_in[15];
    const float* mhw   = (const float*)d_in[16];
    const float* mhb   = (const float*)d_in[17];
    float* out = (float*)d_out;

    // workspace arena (floats)
    float* x0 = (float*)d_ws;                                   //  2,793,472 f
    float* G  = x0 + (size_t)RTOT*NF;                           // 22,347,776 f
    float* x1 = G  + (size_t)RTOT*2048;                         //  5,586,944 f
    float* x2 = x1 + (size_t)RTOT*512;                          //  5,586,944 f
    float* hb = x2 + (size_t)RTOT*512;                          //    349,184 f
    float* cb = hb + (size_t)2*2*SP*HD;                         //    174,592 f (barriers)

    float* qbuf = G;                                            // fp32 q
    float* kbuf = G + (size_t)RTOT*512;                         // fp32 k
    float* vbuf = G + (size_t)2*RTOT*512;                       // fp32 v
    unsigned short* Ppk = (unsigned short*)(G + (size_t)3*RTOT*512); // 8,380,416 ush < 5,586,944 f
    unsigned* bar = (unsigned*)cb;

    // packed-buffer aliases
    unsigned short* x0p = (unsigned short*)x0;
    unsigned short* whh1_hi = (unsigned short*)x0;              // after gemm1
    unsigned short* whh1_lo = whh1_hi + (size_t)524288;         // ends f 524,288
    unsigned short* qw_p = (unsigned short*)(x0 + (size_t)524288);  // x0 region, after whh1
    unsigned short* kw_p = qw_p + (size_t)524288;
    unsigned short* vw_p = kw_p + (size_t)524288;
    unsigned short* mw_p = vw_p + (size_t)524288;               // ends f 1,572,864 < 2,793,472
    unsigned short* wih0_p  = (unsigned short*)x2;
    unsigned short* wih1_p  = wih0_p + (size_t)1048576;
    unsigned short* whh0_hi = wih1_p + (size_t)2097152;
    unsigned short* whh0_lo = whh0_hi + (size_t)524288;
    unsigned short* x1p  = (unsigned short*)x1;
    unsigned short* catp = (unsigned short*)x1;
    unsigned short* x2p = (unsigned short*)x2;

    #define PACKGRID(n) dim3(((n) + 255) / 256)

    // 1. conv+bn+relu+pool -> x0p (packed)
    conv_pool_k<<<dim3(22, B_), 256, 0, stream>>>(in, cw, gamma, beta, x0p);
    // 2. pack Wih0 (octet) into x2 region
    pack8_k<<<PACKGRID(65536), 256, 0, stream>>>(Wih0, wih0_p, 65536);
    // 3. layer-1 input gates: G = x0 @ Wih0^T + b0   (K=256)
    gemm_bf_k<0><<<dim3(16, 86), 256, 0, stream>>>(x0p, wih0_p, b0, G, RTOT, 2048, 256);
    // 4. pack Whh0 (x2 tail), Whh1 (x0, dead after gemm1), Wih1 (x2)
    pack4_k<<<PACKGRID(131072), 256, 0, stream>>>(Whh0, whh0_hi, whh0_lo, 131072);
    pack4_k<<<PACKGRID(131072), 256, 0, stream>>>(Whh1, whh1_hi, whh1_lo, 131072);
    pack8_k<<<PACKGRID(131072), 256, 0, stream>>>(Wih1, wih1_p, 131072);
    // 5. layer-1 scan -> x1p (round-6 persistent, group-local LLC barriers)
    hipMemsetAsync(bar, 0, 22*64*sizeof(unsigned), stream);
    {
        const float* a0 = G; const unsigned short* a1 = whh0_hi; const unsigned short* a2 = whh0_lo;
        float* a3 = hb; unsigned short* a4 = x1p; unsigned* a5 = bar;
        void* kargs[] = {&a0, &a1, &a2, &a3, &a4, &a5};
        hipLaunchCooperativeKernel((void*)lstm_scan_k, dim3(8, 11, 2), dim3(256, 1, 1), kargs, 0, stream);
    }
    // 6. layer-2 input gates: G = x1 @ Wih1^T + b1   (K=512)
    gemm_bf_k<0><<<dim3(16, 86), 256, 0, stream>>>(x1p, wih1_p, b1, G, RTOT, 2048, 512);
    // 7. layer-2 scan -> x2p
    hipMemsetAsync(bar, 0, 22*64*sizeof(unsigned), stream);
    {
        const float* a0 = G; const unsigned short* a1 = whh1_hi; const unsigned short* a2 = whh1_lo;
        float* a3 = hb; unsigned short* a4 = x2p; unsigned* a5 = bar;
        void* kargs[] = {&a0, &a1, &a2, &a3, &a4, &a5};
        hipLaunchCooperativeKernel((void*)lstm_scan_k, dim3(8, 11, 2), dim3(256, 1, 1), kargs, 0, stream);
    }
    // 8. pack QKV/mh weights into x0 region (whh1 dead after scan2)
    pack8_k<<<PACKGRID(32768), 256, 0, stream>>>(Qw,  qw_p, 32768);
    pack8_k<<<PACKGRID(32768), 256, 0, stream>>>(Kw,  kw_p, 32768);
    pack8_k<<<PACKGRID(32768), 256, 0, stream>>>(Vw,  vw_p, 32768);
    pack8_k<<<PACKGRID(32768), 256, 0, stream>>>(mhw, mw_p, 32768);
    // 9. Q/K/V projections (fp32 outputs, coalesced — no transposed scatter)
    gemm_bf_k<0><<<dim3(4, 86), 256, 0, stream>>>(x2p, qw_p, Qb, qbuf, RTOT, 512, 512);
    gemm_bf_k<0><<<dim3(4, 86), 256, 0, stream>>>(x2p, kw_p, Kb, kbuf, RTOT, 512, 512);
    gemm_bf_k<0><<<dim3(4, 86), 256, 0, stream>>>(x2p, vw_p, Vb, vbuf, RTOT, 512, 512);
    // 10. attention: fused scores+softmax -> packed P, then MFMA PV (V
    //     transposed+split in LDS) -> catp
    for (int g = 0; g < B_/GRP; ++g) {
        scores_sm_k<<<dim3(11, GRP, NH_), 256, 0, stream>>>(qbuf, kbuf, Ppk, g);
        pv_bf_k    <<<dim3(6,  GRP, NH_), 256, 0, stream>>>(Ppk, vbuf, catp, g);
    }
    // 11. final linear + relu
    gemm_bf_k<1><<<dim3(4, 86), 256, 0, stream>>>(catp, mw_p, mhb, out, RTOT, 512, 512);
    #undef PACKGRID
}

// Round 11
// 1583.175 us; speedup vs baseline: 2.3842x; 1.0719x over previous
//
#include <hip/hip_runtime.h>
#include <math.h>

// Problem constants
#define B_    32
#define CIN   4
#define SLEN  2048
#define NF    256
#define HD    256          // LSTM hidden per direction
#define SP    341          // post conv+pool sequence length
#define RTOT  (B_*SP)      // 10912 rows
#define NH_   8
#define DH_   64
#define HS    (SP*HD)      // 87296: per-dir h elems
#define SSTR  388          // attn S LDS row stride (floats)

typedef __attribute__((ext_vector_type(8))) short short8;
typedef __attribute__((ext_vector_type(4))) float floatx4;
typedef __attribute__((ext_vector_type(4))) unsigned short ushortx4;
typedef __attribute__((ext_vector_type(8))) unsigned short ushort8;

__device__ __forceinline__ float sigmoidf_(float x) { return 1.0f / (1.0f + expf(-x)); }

__device__ __forceinline__ unsigned short f2bf(float x) {
    unsigned int u = __float_as_uint(x);
    unsigned int r = (u + 0x7FFF + ((u >> 16) & 1)) >> 16;   // RNE
    return (unsigned short)r;
}
__device__ __forceinline__ float bf2f(unsigned short b) {
    return __uint_as_float(((unsigned int)b) << 16);
}

// ---- LLC-coherent (Infinity Cache) access helpers: sc0 sc1 bypass L1/L2 ----
__device__ __forceinline__ void store_f4_llc(float* p, floatx4 v)
{
    asm volatile("global_store_dwordx4 %0, %1, off sc0 sc1" :: "v"(p), "v"(v) : "memory");
}
__device__ __forceinline__ unsigned load_u32_llc(const unsigned* p)
{
    unsigned r;
    asm volatile("global_load_dword %0, %1, off sc0 sc1\n\ts_waitcnt vmcnt(0)"
                 : "=v"(r) : "v"(p) : "memory");
    return r;
}
// 16 x dwordx4 from one base; single trailing waitcnt INSIDE the asm.
__device__ __forceinline__ void load_h16_llc(const float* p, floatx4* r)
{
    asm volatile(
        "global_load_dwordx4 %0, %16, off sc0 sc1\n\t"
        "global_load_dwordx4 %1, %16, off offset:16 sc0 sc1\n\t"
        "global_load_dwordx4 %2, %16, off offset:128 sc0 sc1\n\t"
        "global_load_dwordx4 %3, %16, off offset:144 sc0 sc1\n\t"
        "global_load_dwordx4 %4, %16, off offset:256 sc0 sc1\n\t"
        "global_load_dwordx4 %5, %16, off offset:272 sc0 sc1\n\t"
        "global_load_dwordx4 %6, %16, off offset:384 sc0 sc1\n\t"
        "global_load_dwordx4 %7, %16, off offset:400 sc0 sc1\n\t"
        "global_load_dwordx4 %8, %16, off offset:512 sc0 sc1\n\t"
        "global_load_dwordx4 %9, %16, off offset:528 sc0 sc1\n\t"
        "global_load_dwordx4 %10, %16, off offset:640 sc0 sc1\n\t"
        "global_load_dwordx4 %11, %16, off offset:656 sc0 sc1\n\t"
        "global_load_dwordx4 %12, %16, off offset:768 sc0 sc1\n\t"
        "global_load_dwordx4 %13, %16, off offset:784 sc0 sc1\n\t"
        "global_load_dwordx4 %14, %16, off offset:896 sc0 sc1\n\t"
        "global_load_dwordx4 %15, %16, off offset:912 sc0 sc1\n\t"
        "s_waitcnt vmcnt(0)"
        : "=&v"(r[0]), "=&v"(r[1]), "=&v"(r[2]), "=&v"(r[3]),
          "=&v"(r[4]), "=&v"(r[5]), "=&v"(r[6]), "=&v"(r[7]),
          "=&v"(r[8]), "=&v"(r[9]), "=&v"(r[10]), "=&v"(r[11]),
          "=&v"(r[12]), "=&v"(r[13]), "=&v"(r[14]), "=&v"(r[15])
        : "v"(p)
        : "memory");
}

// ---------------------------------------------------------------------------
// Packed bf16 hi/lo "octet" layout: row of K fp32 -> 2K ushorts; octet o:
// [16o..16o+7]=hi, [16o+8..16o+15]=lo.  K-step 32 = 128 contiguous bytes.
// ---------------------------------------------------------------------------

// Kernel 1: Conv1d(4->256,k13,pad6)+BN+ReLU+MaxPool1d(6) -> x0 packed
__global__ __launch_bounds__(256)
void conv_pool_k(const float* __restrict__ in, const float* __restrict__ cw,
                 const float* __restrict__ gamma, const float* __restrict__ beta,
                 unsigned short* __restrict__ x0p)
{
    const int b  = blockIdx.y;
    const int s0 = blockIdx.x * 16;
    const int co = threadIdx.x;
    __shared__ float ins[CIN][16*6 + 12];
    for (int idx = threadIdx.x; idx < CIN*108; idx += 256) {
        int ci = idx / 108, o = idx % 108;
        int pos = 6*s0 - 6 + o;
        ins[ci][o] = (pos >= 0 && pos < SLEN) ? in[(b*CIN + ci)*SLEN + pos] : 0.0f;
    }
    float wreg[52];
    {
        const float4* wp = (const float4*)(cw + co*52);
        #pragma unroll
        for (int j4 = 0; j4 < 13; ++j4) {
            float4 w4 = wp[j4];
            wreg[j4*4+0]=w4.x; wreg[j4*4+1]=w4.y; wreg[j4*4+2]=w4.z; wreg[j4*4+3]=w4.w;
        }
    }
    const float scale = gamma[co] * (1.0f / sqrtf(1.0f + 1e-5f));
    const float shift = beta[co];
    __syncthreads();
    for (int si = 0; si < 16; ++si) {
        int s = s0 + si;
        if (s >= SP) break;
        float win[CIN][18];
        #pragma unroll
        for (int ci = 0; ci < CIN; ++ci)
            #pragma unroll
            for (int o = 0; o < 18; ++o)
                win[ci][o] = ins[ci][6*si + o];
        float m = -1e30f;
        #pragma unroll
        for (int p6 = 0; p6 < 6; ++p6) {
            float acc = 0.0f;
            #pragma unroll
            for (int ci = 0; ci < CIN; ++ci)
                #pragma unroll
                for (int kk = 0; kk < 13; ++kk)
                    acc += win[ci][p6+kk] * wreg[ci*13+kk];
            float val = acc * scale + shift;
            val = fmaxf(val, 0.0f);
            m = fmaxf(m, val);
        }
        unsigned short hb_ = f2bf(m);
        unsigned short lb_ = f2bf(m - bf2f(hb_));
        size_t rb = (size_t)(b*SP + s)*512 + (size_t)(co >> 3)*16 + (co & 7);
        x0p[rb]     = hb_;
        x0p[rb + 8] = lb_;
    }
}

// Kernel 2a: fp32 -> separate hi/lo pack (for lstm Whh)
__global__ __launch_bounds__(256)
void pack4_k(const float* __restrict__ W, unsigned short* __restrict__ hi,
             unsigned short* __restrict__ lo, int n4)
{
    int i = blockIdx.x * 256 + threadIdx.x;
    if (i >= n4) return;
    float4 x = *((const float4*)W + i);
    float v[4] = {x.x, x.y, x.z, x.w};
    ushortx4 h, l;
    #pragma unroll
    for (int e = 0; e < 4; ++e) {
        unsigned short hb = f2bf(v[e]);
        h[e] = hb;
        l[e] = f2bf(v[e] - bf2f(hb));
    }
    *((ushortx4*)hi + i) = h;
    *((ushortx4*)lo + i) = l;
}

// Kernel 2b: fp32 -> interleaved octet pack (8 elems/thread)
__global__ __launch_bounds__(256)
void pack8_k(const float* __restrict__ W, unsigned short* __restrict__ O, int n8)
{
    int i = blockIdx.x * 256 + threadIdx.x;
    if (i >= n8) return;
    const float4* wp = (const float4*)W + (size_t)i*2;
    float4 a = wp[0], b = wp[1];
    float v[8] = {a.x,a.y,a.z,a.w,b.x,b.y,b.z,b.w};
    ushort8 h, l;
    #pragma unroll
    for (int e = 0; e < 8; ++e) {
        unsigned short hb = f2bf(v[e]);
        h[e] = hb;
        l[e] = f2bf(v[e] - bf2f(hb));
    }
    *(ushort8*)(O + (size_t)i*16)     = h;
    *(ushort8*)(O + (size_t)i*16 + 8) = l;
}

// ---------------------------------------------------------------------------
// Kernel 3: split-bf16 MFMA GEMM, packed octet operands (unchanged).
// ---------------------------------------------------------------------------
template<int RELU>
__global__ __launch_bounds__(256)
void gemm_bf_k(const unsigned short* __restrict__ Ap, const unsigned short* __restrict__ Bp,
               const float* __restrict__ bias, float* __restrict__ C,
               int M, int N, int K)
{
    const int n0 = blockIdx.x * 128;
    const int m0 = blockIdx.y * 128;
    const int tid = threadIdx.x;
    const int lane = tid & 63;
    const int w = tid >> 6;
    const int wm = w >> 1, wn = w & 1;
    const int ln15 = lane & 15, lq = lane >> 4;
    const int l8 = lane >> 3, lj = lane & 7;
    const size_t rstr = 2*(size_t)K;

    __shared__ unsigned short As[128*64];
    __shared__ unsigned short Bs[128*64];

    floatx4 acc[4][4];
    #pragma unroll
    for (int i = 0; i < 4; ++i)
        #pragma unroll
        for (int j = 0; j < 4; ++j) acc[i][j] = (floatx4){0.f, 0.f, 0.f, 0.f};

    int rloc[4];
    #pragma unroll
    for (int c = 0; c < 4; ++c) rloc[c] = w*32 + c*8 + l8;
    const int spos = lj ^ (l8 & 7);

    for (int k0 = 0; k0 < K; k0 += 32) {
        short8 va[4], vb[4];
        #pragma unroll
        for (int c = 0; c < 4; ++c) {
            int gra = m0 + rloc[c]; if (gra >= M) gra = M - 1;
            va[c] = *(const short8*)(Ap + (size_t)gra*rstr + k0*2 + lj*8);
            vb[c] = *(const short8*)(Bp + (size_t)(n0 + rloc[c])*rstr + k0*2 + lj*8);
        }
        __syncthreads();
        #pragma unroll
        for (int c = 0; c < 4; ++c) {
            *(short8*)&As[rloc[c]*64 + spos*8] = va[c];
            *(short8*)&Bs[rloc[c]*64 + spos*8] = vb[c];
        }
        __syncthreads();

        short8 fa_h[4], fa_l[4], fb_h[4], fb_l[4];
        #pragma unroll
        for (int mt = 0; mt < 4; ++mt) {
            const int lr = wm*64 + mt*16 + ln15;
            fa_h[mt] = *(const short8*)&As[lr*64 + (((lq*2  ) ^ (lr&7))*8)];
            fa_l[mt] = *(const short8*)&As[lr*64 + (((lq*2+1) ^ (lr&7))*8)];
        }
        #pragma unroll
        for (int nt = 0; nt < 4; ++nt) {
            const int lr = wn*64 + nt*16 + ln15;
            fb_h[nt] = *(const short8*)&Bs[lr*64 + (((lq*2  ) ^ (lr&7))*8)];
            fb_l[nt] = *(const short8*)&Bs[lr*64 + (((lq*2+1) ^ (lr&7))*8)];
        }
        #pragma unroll
        for (int mt = 0; mt < 4; ++mt)
            #pragma unroll
            for (int nt = 0; nt < 4; ++nt) {
                acc[mt][nt] = __builtin_amdgcn_mfma_f32_16x16x32_bf16(fa_l[mt], fb_h[nt], acc[mt][nt], 0, 0, 0);
                acc[mt][nt] = __builtin_amdgcn_mfma_f32_16x16x32_bf16(fa_h[mt], fb_l[nt], acc[mt][nt], 0, 0, 0);
                acc[mt][nt] = __builtin_amdgcn_mfma_f32_16x16x32_bf16(fa_h[mt], fb_h[nt], acc[mt][nt], 0, 0, 0);
            }
    }

    #pragma unroll
    for (int nt = 0; nt < 4; ++nt) {
        const int n = n0 + wn*64 + nt*16 + ln15;
        const float bv = bias[n];
        #pragma unroll
        for (int mt = 0; mt < 4; ++mt) {
            const int mbase = m0 + wm*64 + mt*16 + lq*4;
            #pragma unroll
            for (int r = 0; r < 4; ++r) {
                int m = mbase + r;
                if (m < M) {
                    float val = acc[mt][nt][r] + bv;
                    if (RELU) val = fmaxf(val, 0.0f);
                    C[(size_t)m*N + n] = val;
                }
            }
        }
    }
}

// ---------------------------------------------------------------------------
// Kernel 3b: PERSISTENT LSTM scan, GROUP-LOCAL LLC barrier (round-6, verified:
// 393 us/layer).  22 groups of 8 j-blocks; c in regs; h via sc0/sc1 dbuf.
// ---------------------------------------------------------------------------
__global__ __launch_bounds__(256)
void lstm_scan_k(const float* __restrict__ G,              // [32*341][2048]
                 const unsigned short* __restrict__ Whi,   // [2][1024][256]
                 const unsigned short* __restrict__ Wlo,
                 float* __restrict__ hb,                   // [2][2*341*256] dbuf
                 unsigned short* __restrict__ x_out,       // packed rows of 512
                 unsigned* __restrict__ bar)               // [22*64], zeroed
{
    const int j0 = blockIdx.x * 32;
    const int m0 = blockIdx.y * 32;
    const int d  = blockIdx.z;
    const int tid = threadIdx.x;
    const int w = tid >> 6, lane = tid & 63;
    const int mhalf = w & 1, gpair = w >> 1;
    const int ln15 = lane & 15, lq = lane >> 4;
    const size_t hsz = (size_t)2*SP*HD;
    unsigned* gbar = bar + (size_t)(blockIdx.y*2 + blockIdx.z)*64;

    __shared__ float Csh[32][132];

    int am = m0 + mhalf*16 + ln15; if (am > SP-1) am = SP-1;
    const int akoff = lq * 8;

    const unsigned short* WhiD = Whi + (size_t)d*1024*256;
    const unsigned short* WloD = Wlo + (size_t)d*1024*256;
    int nrow[4];
    #pragma unroll
    for (int t = 0; t < 4; ++t)
        nrow[t] = (gpair*2 + (t>>1))*256 + j0 + (t&1)*16 + ln15;

    const int emloc = tid >> 3;
    const int ej4   = (tid & 7) * 4;
    const int em    = m0 + emloc;

    floatx4 creg = (floatx4){0.f, 0.f, 0.f, 0.f};

    for (int s = 0; s < B_; ++s) {
        const int t_in = d ? (B_ - 1 - s) : s;
        float* hbuf_in  = hb + (size_t)(s & 1)*hsz;
        float* hbuf_out = hb + (size_t)((s+1) & 1)*hsz;

        floatx4 acc[4];
        #pragma unroll
        for (int t = 0; t < 4; ++t) acc[t] = (floatx4){0.f, 0.f, 0.f, 0.f};

        if (s > 0) {
            const float* p = hbuf_in + (size_t)d*HS + (size_t)am*HD + akoff;
            floatx4 hr[16];
            load_h16_llc(p, hr);
            #pragma unroll
            for (int kk = 0; kk < 8; ++kk) {
                const int ko = kk*32 + akoff;
                float vv[8] = {hr[2*kk][0], hr[2*kk][1], hr[2*kk][2], hr[2*kk][3],
                               hr[2*kk+1][0], hr[2*kk+1][1], hr[2*kk+1][2], hr[2*kk+1][3]};
                short8 ahi, alo;
                #pragma unroll
                for (int e = 0; e < 8; ++e) {
                    unsigned short hb16 = f2bf(vv[e]);
                    ahi[e] = (short)hb16;
                    alo[e] = (short)f2bf(vv[e] - bf2f(hb16));
                }
                #pragma unroll
                for (int t = 0; t < 4; ++t) {
                    short8 bhi = *(const short8*)(WhiD + (size_t)nrow[t]*HD + ko);
                    short8 blo = *(const short8*)(WloD + (size_t)nrow[t]*HD + ko);
                    acc[t] = __builtin_amdgcn_mfma_f32_16x16x32_bf16(alo, bhi, acc[t], 0, 0, 0);
                    acc[t] = __builtin_amdgcn_mfma_f32_16x16x32_bf16(ahi, blo, acc[t], 0, 0, 0);
                    acc[t] = __builtin_amdgcn_mfma_f32_16x16x32_bf16(ahi, bhi, acc[t], 0, 0, 0);
                }
            }
        }

        #pragma unroll
        for (int t = 0; t < 4; ++t) {
            int col = gpair*64 + (t>>1)*32 + (t&1)*16 + ln15;
            int rb  = mhalf*16 + lq*4;
            #pragma unroll
            for (int r = 0; r < 4; ++r)
                Csh[rb + r][col] = acc[t][r];
        }
        __syncthreads();

        if (em < SP) {
            size_t gb = ((size_t)t_in*SP + em)*2048 + (size_t)d*1024 + j0 + ej4;
            float4 gi4 = *(const float4*)&G[gb];
            float4 gf4 = *(const float4*)&G[gb + 256];
            float4 gg4 = *(const float4*)&G[gb + 512];
            float4 go4 = *(const float4*)&G[gb + 768];
            float hv[4];
            #pragma unroll
            for (int e = 0; e < 4; ++e) {
                float gi = Csh[emloc][     ej4+e] + (&gi4.x)[e];
                float gf = Csh[emloc][32 + ej4+e] + (&gf4.x)[e];
                float gg = Csh[emloc][64 + ej4+e] + (&gg4.x)[e];
                float go = Csh[emloc][96 + ej4+e] + (&go4.x)[e];
                float cn = sigmoidf_(gf)*creg[e] + sigmoidf_(gi)*tanhf(gg);
                creg[e] = cn;
                hv[e] = sigmoidf_(go)*tanhf(cn);
            }
            size_t cbase = ((size_t)d*SP + em)*HD + j0 + ej4;
            floatx4 ho = (floatx4){hv[0], hv[1], hv[2], hv[3]};
            store_f4_llc(&hbuf_out[cbase], ho);
            const int colg = d*HD + j0 + ej4;
            size_t xb = ((size_t)t_in*SP + em)*1024 + (size_t)(colg >> 3)*16 + (colg & 7);
            ushortx4 xh, xl;
            #pragma unroll
            for (int e = 0; e < 4; ++e) {
                unsigned short hb16 = f2bf(hv[e]);
                xh[e] = hb16;
                xl[e] = f2bf(hv[e] - bf2f(hb16));
            }
            *(ushortx4*)&x_out[xb]     = xh;
            *(ushortx4*)&x_out[xb + 8] = xl;
        }

        if (s < B_ - 1) {
            asm volatile("s_waitcnt vmcnt(0)" ::: "memory");
            __syncthreads();
            if (tid == 0) {
                atomicAdd(gbar, 1u);
                const unsigned target = (unsigned)(s + 1) * 8u;
                while (load_u32_llc(gbar) < target)
                    __builtin_amdgcn_s_sleep(2);
            }
            __syncthreads();
        }
    }
}

// ---------------------------------------------------------------------------
// Kernel 4: FUSED attention — ONE launch for all (batch, head, q-tile).
// Block = 16 q-rows x one (bg, h).  Grid (22, 32, 8) = 5632 blocks.
//   Phase A: 6 kv-chunks of QK^T (round-9 dot/RPE/softmax math, 1 row/thread,
//            tx-group shfl reduce) -> normalized P fp32 into LDS S[16][388].
//   Phase B: 6 V-chunks of PV on VALU (S broadcast reads + float4 V reads).
//   P never touches global; no per-group loop.  Epilogue writes catp packed.
// ---------------------------------------------------------------------------
__global__ __launch_bounds__(256)
void attn_k(const float* __restrict__ q, const float* __restrict__ k,
            const float* __restrict__ v, unsigned short* __restrict__ catp)
{
    const int h = blockIdx.z, bg = blockIdx.y;
    const int q0 = blockIdx.x * 16;
    const int tid = threadIdx.x;
    const int tx = tid & 15, ty = tid >> 4;
    __shared__ float qs[16][68];
    __shared__ float st[64][68];      // ks in phase A, vs in phase B
    __shared__ float S[16][SSTR];

    // stage q: 16 rows x 64 dims
    {
        int jr = tid >> 4, c4 = (tid & 15) * 4;
        int qq = q0 + jr; if (qq > SP-1) qq = SP-1;
        *(float4*)&qs[jr][c4] = *(const float4*)&q[((size_t)bg*SP + qq)*512 + h*64 + c4];
    }

    float sv[24];
    for (int kc = 0; kc < 6; ++kc) {
        __syncthreads();
        {
            int jr = tid >> 2, c16 = (tid & 3) * 16;
            int kr = kc*64 + jr; if (kr > SP-1) kr = SP-1;
            const float* kp = &k[((size_t)bg*SP + kr)*512 + h*64 + c16];
            #pragma unroll
            for (int u = 0; u < 4; ++u)
                *(float4*)&st[jr][c16 + u*4] = *(const float4*)(kp + u*4);
        }
        __syncthreads();
        float a_[4] = {0.f, 0.f, 0.f, 0.f};
        for (int d4 = 0; d4 < 64; d4 += 4) {
            float4 a0 = *(const float4*)&qs[ty][d4];
            float4 b[4];
            #pragma unroll
            for (int j = 0; j < 4; ++j) b[j] = *(const float4*)&st[tx + 16*j][d4];
            #pragma unroll
            for (int j = 0; j < 4; ++j)
                a_[j] += a0.x*b[j].x + a0.y*b[j].y + a0.z*b[j].z + a0.w*b[j].w;
        }
        #pragma unroll
        for (int j = 0; j < 4; ++j) sv[kc*4 + j] = a_[j];
    }

    // RPE + softmax (identical math to round-9 scores_sm_k — verified)
    {
        const int qq = q0 + ty;
        int r0 = 6*qq - 1; if (r0 < 0) r0 = 0;
        int r1 = 6*qq + 7; if (r1 > SLEN-1) r1 = SLEN-1;
        float m = -1e30f;
        #pragma unroll
        for (int jj = 0; jj < 24; ++jj) {
            const int col = (jj >> 2)*64 + (jj & 3)*16 + tx;
            float s;
            if (col < SP) {
                int c0 = 6*col - 1; if (c0 < 0) c0 = 0;
                int c1 = 6*col + 7;
                int dd1 = c1 - r0; if (dd1 < 0) dd1 = -dd1;
                int dd2 = r1 - c0; if (dd2 < 0) dd2 = -dd2;
                int den = dd1 > dd2 ? dd1 : dd2;
                s = (sv[jj] * 0.125f) * 2047.0f / (float)den;
            } else s = -1e30f;
            sv[jj] = s;
            m = fmaxf(m, s);
        }
        #pragma unroll
        for (int o = 1; o < 16; o <<= 1) m = fmaxf(m, __shfl_xor(m, o, 64));
        float sum = 0.0f;
        #pragma unroll
        for (int jj = 0; jj < 24; ++jj) {
            float vv_ = expf(sv[jj] - m);
            sv[jj] = vv_;
            sum += vv_;
        }
        #pragma unroll
        for (int o = 1; o < 16; o <<= 1) sum += __shfl_xor(sum, o, 64);
        const float inv = 1.0f / sum;
        #pragma unroll
        for (int jj = 0; jj < 24; ++jj) {
            const int col = (jj >> 2)*64 + (jj & 3)*16 + tx;
            S[ty][col] = sv[jj] * inv;     // cols 341..383: exactly 0
        }
    }
    __syncthreads();   // S complete; phase-A st reads complete

    // Phase B: O = P @ V
    float o[4] = {0.f, 0.f, 0.f, 0.f};
    for (int kc = 0; kc < 6; ++kc) {
        {
            int jr = tid >> 2, c16 = (tid & 3) * 16;
            int kr = kc*64 + jr; if (kr > SP-1) kr = SP-1;   // clamp: S=0 there
            const float* vp = &v[((size_t)bg*SP + kr)*512 + h*64 + c16];
            #pragma unroll
            for (int u = 0; u < 4; ++u)
                *(float4*)&st[jr][c16 + u*4] = *(const float4*)(vp + u*4);
        }
        __syncthreads();
        for (int kk = 0; kk < 64; ++kk) {
            float p = S[ty][kc*64 + kk];                 // broadcast (free)
            float4 vv = *(const float4*)&st[kk][tx*4];   // 2 lanes/bank (free)
            o[0] += p*vv.x; o[1] += p*vv.y; o[2] += p*vv.z; o[3] += p*vv.w;
        }
        __syncthreads();
    }

    // epilogue: catp packed (relu)
    const int em = q0 + ty;
    if (em < SP) {
        const int colg = h*64 + tx*4;
        size_t xb = ((size_t)bg*SP + em)*1024 + (size_t)((colg >> 3)*16 + (colg & 7));
        ushortx4 xh, xl;
        #pragma unroll
        for (int e = 0; e < 4; ++e) {
            float val = fmaxf(o[e], 0.0f);
            unsigned short hb16 = f2bf(val);
            xh[e] = hb16;
            xl[e] = f2bf(val - bf2f(hb16));
        }
        *(ushortx4*)&catp[xb]     = xh;
        *(ushortx4*)&catp[xb + 8] = xl;
    }
}

// ---------------------------------------------------------------------------
extern "C" void kernel_launch(void* const* d_in, const int* in_sizes, int n_in,
                              void* d_out, int out_size, void* d_ws, size_t ws_size,
                              hipStream_t stream)
{
    (void)in_sizes; (void)n_in; (void)out_size; (void)ws_size;
    const float* in    = (const float*)d_in[0];
    const float* cw    = (const float*)d_in[1];
    const float* gamma = (const float*)d_in[2];
    const float* beta  = (const float*)d_in[3];
    const float* Wih0  = (const float*)d_in[4];
    const float* Whh0  = (const float*)d_in[5];
    const float* b0    = (const float*)d_in[6];
    const float* Wih1  = (const float*)d_in[7];
    const float* Whh1  = (const float*)d_in[8];
    const float* b1    = (const float*)d_in[9];
    const float* Qw    = (const float*)d_in[10];
    const float* Qb    = (const float*)d_in[11];
    const float* Kw    = (const float*)d_in[12];
    const float* Kb    = (const float*)d_in[13];
    const float* Vw    = (const float*)d_in[14];
    const float* Vb    = (const float*)d_in[15];
    const float* mhw   = (const float*)d_in[16];
    const float* mhb   = (const float*)d_in[17];
    float* out = (float*)d_out;

    // workspace arena (floats)
    float* x0 = (float*)d_ws;                                   //  2,793,472 f
    float* G  = x0 + (size_t)RTOT*NF;                           // 22,347,776 f
    float* x1 = G  + (size_t)RTOT*2048;                         //  5,586,944 f
    float* x2 = x1 + (size_t)RTOT*512;                          //  5,586,944 f
    float* hb = x2 + (size_t)RTOT*512;                          //    349,184 f
    float* cb = hb + (size_t)2*2*SP*HD;                         //    174,592 f (barriers)

    float* qbuf = G;                                            // fp32 q
    float* kbuf = G + (size_t)RTOT*512;                         // fp32 k
    float* vbuf = G + (size_t)2*RTOT*512;                       // fp32 v
    unsigned* bar = (unsigned*)cb;

    // packed-buffer aliases
    unsigned short* x0p = (unsigned short*)x0;
    unsigned short* whh1_hi = (unsigned short*)x0;              // after gemm1
    unsigned short* whh1_lo = whh1_hi + (size_t)524288;         // ends f 524,288
    unsigned short* qw_p = (unsigned short*)(x0 + (size_t)524288);  // x0 region, after whh1
    unsigned short* kw_p = qw_p + (size_t)524288;
    unsigned short* vw_p = kw_p + (size_t)524288;
    unsigned short* mw_p = vw_p + (size_t)524288;               // ends f 1,572,864 < 2,793,472
    unsigned short* wih0_p  = (unsigned short*)x2;
    unsigned short* wih1_p  = wih0_p + (size_t)1048576;
    unsigned short* whh0_hi = wih1_p + (size_t)2097152;
    unsigned short* whh0_lo = whh0_hi + (size_t)524288;
    unsigned short* x1p  = (unsigned short*)x1;
    unsigned short* catp = (unsigned short*)x1;
    unsigned short* x2p = (unsigned short*)x2;

    #define PACKGRID(n) dim3(((n) + 255) / 256)

    // 1. conv+bn+relu+pool -> x0p (packed)
    conv_pool_k<<<dim3(22, B_), 256, 0, stream>>>(in, cw, gamma, beta, x0p);
    // 2. pack Wih0 (octet) into x2 region
    pack8_k<<<PACKGRID(65536), 256, 0, stream>>>(Wih0, wih0_p, 65536);
    // 3. layer-1 input gates: G = x0 @ Wih0^T + b0   (K=256)
    gemm_bf_k<0><<<dim3(16, 86), 256, 0, stream>>>(x0p, wih0_p, b0, G, RTOT, 2048, 256);
    // 4. pack Whh0 (x2 tail), Whh1 (x0, dead after gemm1), Wih1 (x2)
    pack4_k<<<PACKGRID(131072), 256, 0, stream>>>(Whh0, whh0_hi, whh0_lo, 131072);
    pack4_k<<<PACKGRID(131072), 256, 0, stream>>>(Whh1, whh1_hi, whh1_lo, 131072);
    pack8_k<<<PACKGRID(131072), 256, 0, stream>>>(Wih1, wih1_p, 131072);
    // 5. layer-1 scan -> x1p (round-6 persistent, group-local LLC barriers)
    hipMemsetAsync(bar, 0, 22*64*sizeof(unsigned), stream);
    {
        const float* a0 = G; const unsigned short* a1 = whh0_hi; const unsigned short* a2 = whh0_lo;
        float* a3 = hb; unsigned short* a4 = x1p; unsigned* a5 = bar;
        void* kargs[] = {&a0, &a1, &a2, &a3, &a4, &a5};
        hipLaunchCooperativeKernel((void*)lstm_scan_k, dim3(8, 11, 2), dim3(256, 1, 1), kargs, 0, stream);
    }
    // 6. layer-2 input gates: G = x1 @ Wih1^T + b1   (K=512)
    gemm_bf_k<0><<<dim3(16, 86), 256, 0, stream>>>(x1p, wih1_p, b1, G, RTOT, 2048, 512);
    // 7. layer-2 scan -> x2p
    hipMemsetAsync(bar, 0, 22*64*sizeof(unsigned), stream);
    {
        const float* a0 = G; const unsigned short* a1 = whh1_hi; const unsigned short* a2 = whh1_lo;
        float* a3 = hb; unsigned short* a4 = x2p; unsigned* a5 = bar;
        void* kargs[] = {&a0, &a1, &a2, &a3, &a4, &a5};
        hipLaunchCooperativeKernel((void*)lstm_scan_k, dim3(8, 11, 2), dim3(256, 1, 1), kargs, 0, stream);
    }
    // 8. pack QKV/mh weights into x0 region (whh1 dead after scan2)
    pack8_k<<<PACKGRID(32768), 256, 0, stream>>>(Qw,  qw_p, 32768);
    pack8_k<<<PACKGRID(32768), 256, 0, stream>>>(Kw,  kw_p, 32768);
    pack8_k<<<PACKGRID(32768), 256, 0, stream>>>(Vw,  vw_p, 32768);
    pack8_k<<<PACKGRID(32768), 256, 0, stream>>>(mhw, mw_p, 32768);
    // 9. Q/K/V projections (fp32 outputs, coalesced)
    gemm_bf_k<0><<<dim3(4, 86), 256, 0, stream>>>(x2p, qw_p, Qb, qbuf, RTOT, 512, 512);
    gemm_bf_k<0><<<dim3(4, 86), 256, 0, stream>>>(x2p, kw_p, Kb, kbuf, RTOT, 512, 512);
    gemm_bf_k<0><<<dim3(4, 86), 256, 0, stream>>>(x2p, vw_p, Vb, vbuf, RTOT, 512, 512);
    // 10. attention: ONE fused launch (QK^T + RPE + softmax + PV) -> catp
    attn_k<<<dim3(22, B_, NH_), 256, 0, stream>>>(qbuf, kbuf, vbuf, catp);
    // 11. final linear + relu
    gemm_bf_k<1><<<dim3(4, 86), 256, 0, stream>>>(catp, mw_p, mhb, out, RTOT, 512, 512);
    #undef PACKGRID
}